// Round 2
// baseline (2961.230 us; speedup 1.0000x reference)
//
#include <hip/hip_runtime.h>
#include <hip/hip_bf16.h>

typedef __hip_bfloat16 bf16;
typedef __attribute__((ext_vector_type(8))) short short8;
typedef __attribute__((ext_vector_type(4))) float f32x4;

#define NN 20000
#define NE 80000
#define DD 128
#define NITER 15
#define HSTRIDE 136   // 272 B row stride: 16B-aligned rows, 2-way LDS aliasing (free)

__device__ inline float bfbits2f(unsigned int hi16) {
  union { unsigned int u; float f; } c; c.u = hi16; return c.f;
}

__device__ inline float readin(const void* p, int i, int fl) {
  return fl ? (float)((const bf16*)p)[i] : ((const float*)p)[i];
}

// ---------------------------------------------------------------------------
// detzero: blocks 0..78 zero counts; block 79 runs dtype detection.
// flag = 1 -> bf16 inputs ; flag = 0 -> fp32 inputs.
// ---------------------------------------------------------------------------
__global__ void detzero_kernel(const unsigned short* __restrict__ x,
                               int* __restrict__ counts, int* __restrict__ flag) {
  const int bid = blockIdx.x, t = threadIdx.x;
  if (bid < 79) {
    int i = bid * 256 + t;
    if (i < NN) counts[i] = 0;
    return;
  }
  __shared__ int cs[256], ct[256];
  int sane = 0, tot = 0;
  for (int i = 2 * t; i < 16384; i += 512) {
    unsigned short v = x[i];
    int e = (v >> 7) & 0xFF;
    tot++;
    if (v == 0 || (e >= 80 && e <= 170)) sane++;
  }
  cs[t] = sane; ct[t] = tot;
  __syncthreads();
  for (int o = 128; o > 0; o >>= 1) {
    if (t < o) { cs[t] += cs[t + o]; ct[t] += ct[t + o]; }
    __syncthreads();
  }
  if (t == 0) *flag = (cs[0] * 10 > ct[0] * 7) ? 1 : 0;
}

// ---------------------------------------------------------------------------
// convert_all: one grid-stride kernel for every input canonicalization.
// ---------------------------------------------------------------------------
#define CX  (NN * DD)
#define CE  (NE * DD)
#define CW0 (NITER * 384 * DD)
#define CW1 (NITER * 128 * DD)
#define CNW0 (NITER * 256 * DD)
#define CB  (NITER * DD)
#define BX0 CX
#define BX1 (BX0 + CE)
#define BX7 (BX1 + CW0 + CW1 + CW1 + CNW0 + CW1 + CW1)
#define BX8 (BX7 + 10 * CB)

struct CvtP {
  const void *x, *e;
  const void* w[6];
  bf16 *xb, *eb;
  bf16* wt[6];
  const void* bs[10];
  float* bd[10];
  const int* flag;
};

__global__ void convert_all(CvtP P) {
  const int fl = *P.flag;
  const int gstride = gridDim.x * 256;
  for (int i = blockIdx.x * 256 + threadIdx.x; i < BX8; i += gstride) {
    if (i < BX0) {
      P.xb[i] = (bf16)readin(P.x, i, fl);
    } else if (i < BX1) {
      P.eb[i - BX0] = (bf16)readin(P.e, i - BX0, fl);
    } else if (i < BX7) {
      int j = i - BX1, w;
      if (j < CW0) { w = 0; }
      else if ((j -= CW0) < CW1) { w = 1; }
      else if ((j -= CW1) < CW1) { w = 2; }
      else if ((j -= CW1) < CNW0) { w = 3; }
      else if ((j -= CNW0) < CW1) { w = 4; }
      else { j -= CW1; w = 5; }
      const int K = (w == 0) ? 384 : (w == 3) ? 256 : 128;
      float v = readin(P.w[w], j, fl);
      int it = j / (K * DD);
      int rem = j - it * K * DD;
      int k = rem >> 7, n = rem & 127;
      P.wt[w][(size_t)it * K * DD + (size_t)n * K + k] = (bf16)v;
    } else {
      int j = i - BX7;
      int b = j / CB, r = j - b * CB;
      P.bd[b][r] = readin(P.bs[b], r, fl);
    }
  }
}

// ---------------------------------------------------------------------------
// Fused 3-layer MLP — barrier-free, MI=1 (16 rows/wave, 64-row blocks).
//
// Round-1 lesson: barrier-free direct-B works ONLY with enough resident
// waves. MI=2 collapsed occupancy to 19% (grid 625, LDS 34.8K) -> 76 us.
// This version: MI=1, no Bls at all (B fragments read straight from L1/L2 —
// weights are <=162 KB/iter, hot), LDS = H tile only (17.4 KB) -> grid 1250,
// ~4-5 blocks/CU, ~55-60% occupancy. Zero __syncthreads in the whole kernel:
// H rows are wave-private, so waves free-run and the compiler software-
// pipelines the fully unrolled slab loops.
//
// AMODE 1: A0 = concat(xb[row[m]], xb[col[m]], eb[m])  (K0=384)
// AMODE 2: A0 = concat(xb[m], agg[m]), agg computed IN-KERNEL from CSR
//          into a wave-private LDS stripe (fuses the old aggregate_kernel
//          into the node MLP's idle latency slots; node grid is only 313
//          blocks = 1.2 blocks/CU, so this work is nearly free).
// ---------------------------------------------------------------------------
template<int K0, int AMODE>
__global__ __launch_bounds__(256, 4) void fused_mlp(
    const bf16* S0b,                 // xb (aliases st for AMODE 2)
    const bf16* S1b,                 // eb (AMODE 1: A-seg2, aliases st; AMODE 2: agg source)
    const int*  __restrict__ eidx,
    const int*  __restrict__ offs,   // AMODE 2 only (CSR)
    const int*  __restrict__ sorted, // AMODE 2 only (CSR)
    const bf16* __restrict__ W0t, const bf16* __restrict__ W1t,
    const bf16* __restrict__ W2t,
    const float* __restrict__ b0, const float* __restrict__ b1,
    const float* __restrict__ b2,
    const float* __restrict__ gamma, const float* __restrict__ beta,
    bf16* st, int M)
{
  __shared__ __align__(16) bf16 Hls[64 * HSTRIDE];
  __shared__ __align__(16) bf16 Als[(AMODE == 2) ? 64 * HSTRIDE : 16];

  const int tid  = threadIdx.x;
  const int lane = tid & 63;
  const int wv   = tid >> 6;
  const int l15  = lane & 15, quad = lane >> 4;
  const int m0   = blockIdx.x * 64;

  const int rowm = min(m0 + wv * 16 + l15, M - 1);
  int ir = 0, ic = 0;
  if (AMODE == 1) { ir = eidx[rowm]; ic = eidx[NE + rowm]; }

  // ---- AMODE 2 prologue: CSR aggregate into wave-private LDS rows --------
  if (AMODE == 2) {
    for (int g = 0; g < 16; ++g) {
      const int node = min(m0 + wv * 16 + g, M - 1);
      const int s = offs[node], t = offs[node + 1];
      float a0 = 0.f, a1 = 0.f;
      for (int i = s; i < t; i++) {
        const int e = sorted[i];
        unsigned int v = *(const unsigned int*)(S1b + (size_t)e * DD + 2 * lane);
        a0 += bfbits2f(v << 16);
        a1 += bfbits2f(v & 0xFFFF0000u);
      }
      bf16 o0 = (bf16)a0, o1 = (bf16)a1;
      unsigned int pack = (unsigned int)(*(unsigned short*)&o0)
                        | ((unsigned int)(*(unsigned short*)&o1) << 16);
      *(unsigned int*)&Als[(wv * 16 + g) * HSTRIDE + 2 * lane] = pack;
    }
  }

  // 8 per-lane B-fragment base pointers for the current weight matrix.
  const bf16* pB[8];
  auto setB = [&](const bf16* __restrict__ W, int K) {
#pragma unroll
    for (int ni = 0; ni < 8; ni++)
      pB[ni] = W + (size_t)(ni * 16 + l15) * K + quad * 8;
  };

  f32x4 acc[8];
  auto zacc = [&]() {
#pragma unroll
    for (int ni = 0; ni < 8; ni++) acc[ni] = (f32x4){0.f, 0.f, 0.f, 0.f};
  };

  auto gatherA = [&](int kk) -> short8 {
    const int ks = (kk & 127) + quad * 8;
    if (AMODE == 1) {
      const int seg = kk >> 7;
      const bf16* base = (seg == 0) ? S0b + (size_t)ir * DD
                       : (seg == 1) ? S0b + (size_t)ic * DD
                                    : S1b + (size_t)rowm * DD;
      return *(const short8*)(base + ks);
    } else {
      if (kk >> 7) return *(const short8*)&Als[(wv * 16 + l15) * HSTRIDE + ks];
      return *(const short8*)(S0b + (size_t)rowm * DD + ks);
    }
  };

  auto writeH = [&](const float* __restrict__ bias) {
    float bv[8];
#pragma unroll
    for (int ni = 0; ni < 8; ni++) bv[ni] = bias[ni * 16 + l15];
#pragma unroll
    for (int r = 0; r < 4; r++) {
      const int row = wv * 16 + quad * 4 + r;
#pragma unroll
      for (int ni = 0; ni < 8; ni++)
        Hls[row * HSTRIDE + ni * 16 + l15] = (bf16)fmaxf(acc[ni][r] + bv[ni], 0.f);
    }
  };

  // Phase 1: A gathered (global / LDS agg), B direct from global (L1/L2).
  zacc();
  setB(W0t, K0);
#pragma unroll
  for (int s = 0; s < K0 / 32; s++) {
    const int kk = s * 32;
    short8 bfr[8];
#pragma unroll
    for (int ni = 0; ni < 8; ni++) bfr[ni] = *(const short8*)(pB[ni] + kk);
    short8 a = gatherA(kk);
#pragma unroll
    for (int ni = 0; ni < 8; ni++)
      acc[ni] = __builtin_amdgcn_mfma_f32_16x16x32_bf16(a, bfr[ni], acc[ni], 0, 0, 0);
  }
  writeH(b0);

  // Phase 2: A from wave-private H rows in LDS, B direct from global.
  zacc();
  setB(W1t, 128);
#pragma unroll
  for (int s = 0; s < 4; s++) {
    const int kk = s * 32;
    short8 bfr[8];
#pragma unroll
    for (int ni = 0; ni < 8; ni++) bfr[ni] = *(const short8*)(pB[ni] + kk);
    short8 a = *(const short8*)&Hls[(wv * 16 + l15) * HSTRIDE + kk + quad * 8];
#pragma unroll
    for (int ni = 0; ni < 8; ni++)
      acc[ni] = __builtin_amdgcn_mfma_f32_16x16x32_bf16(a, bfr[ni], acc[ni], 0, 0, 0);
  }
  writeH(b1);

  // Phase 3 + LN + residual.
  zacc();
  setB(W2t, 128);
#pragma unroll
  for (int s = 0; s < 4; s++) {
    const int kk = s * 32;
    short8 bfr[8];
#pragma unroll
    for (int ni = 0; ni < 8; ni++) bfr[ni] = *(const short8*)(pB[ni] + kk);
    short8 a = *(const short8*)&Hls[(wv * 16 + l15) * HSTRIDE + kk + quad * 8];
#pragma unroll
    for (int ni = 0; ni < 8; ni++)
      acc[ni] = __builtin_amdgcn_mfma_f32_16x16x32_bf16(a, bfr[ni], acc[ni], 0, 0, 0);
  }

  float bv[8], gv[8], btv[8];
#pragma unroll
  for (int ni = 0; ni < 8; ni++) {
    const int col = ni * 16 + l15;
    bv[ni] = b2[col]; gv[ni] = gamma[col]; btv[ni] = beta[col];
  }
#pragma unroll
  for (int r = 0; r < 4; r++) {
    float a = 0.f, bq = 0.f;
#pragma unroll
    for (int ni = 0; ni < 8; ni++) {
      const float v = acc[ni][r] + bv[ni];
      a += v; bq += v * v;
    }
#pragma unroll
    for (int off = 1; off < 16; off <<= 1) {
      a  += __shfl_xor(a, off);
      bq += __shfl_xor(bq, off);
    }
    const float mu = a * (1.0f / 128.0f);
    const float var = fmaxf(bq * (1.0f / 128.0f) - mu * mu, 0.0f);
    const float rs = rsqrtf(var + 1e-5f);
    const int m = m0 + wv * 16 + quad * 4 + r;
    if (m < M) {
#pragma unroll
      for (int ni = 0; ni < 8; ni++) {
        const int col = ni * 16 + l15;
        const float v = acc[ni][r] + bv[ni];
        const float lnv = (v - mu) * rs * gv[ni] + btv[ni];
        const size_t idx = (size_t)m * DD + col;
        st[idx] = (bf16)(lnv + (float)st[idx]);
      }
    }
  }
}

// --------------------------- CSR build ------------------------------------
__global__ void hist_kernel(const int* __restrict__ eidx, int* __restrict__ counts) {
  int e = blockIdx.x * 256 + threadIdx.x;
  if (e < NE) atomicAdd(&counts[eidx[NE + e]], 1);
}

__global__ void scan_kernel(const int* __restrict__ counts, int* __restrict__ offs,
                            int* __restrict__ cursor) {
  __shared__ int sums[1024];
  const int t = threadIdx.x;
  const int base = t * 20;
  int local[20];
  int s = 0;
  for (int i = 0; i < 20; i++) {
    int idx = base + i;
    int c = (idx < NN) ? counts[idx] : 0;
    local[i] = s; s += c;
  }
  sums[t] = s;
  __syncthreads();
  for (int off = 1; off < 1024; off <<= 1) {
    int v = 0;
    if (t >= off) v = sums[t - off];
    __syncthreads();
    if (t >= off) sums[t] += v;
    __syncthreads();
  }
  int excl = (t == 0) ? 0 : sums[t - 1];
  for (int i = 0; i < 20; i++) {
    int idx = base + i;
    if (idx < NN) { offs[idx] = excl + local[i]; cursor[idx] = 0; }
  }
  if (t == 1023) offs[NN] = sums[1023];
}

__global__ void fill_kernel(const int* __restrict__ eidx, const int* __restrict__ offs,
                            int* __restrict__ cursor, int* __restrict__ sorted) {
  int e = blockIdx.x * 256 + threadIdx.x;
  if (e < NE) {
    int n = eidx[NE + e];
    int p = atomicAdd(&cursor[n], 1);
    sorted[offs[n] + p] = e;
  }
}

// bf16 states -> d_out in detected dtype
__global__ void outwb_kernel(const bf16* __restrict__ xb, const bf16* __restrict__ eb,
                             void* __restrict__ out, const int* __restrict__ flag) {
  int i = blockIdx.x * 256 + threadIdx.x;
  const int nx = NN * DD, total = (NN + NE) * DD;
  if (i < total) {
    bf16 v = (i < nx) ? xb[i] : eb[i - nx];
    if (*flag) ((bf16*)out)[i] = v;
    else       ((float*)out)[i] = (float)v;
  }
}

// ---------------------------------------------------------------------------
extern "C" void kernel_launch(void* const* d_in, const int* in_sizes, int n_in,
                              void* d_out, int out_size, void* d_ws, size_t ws_size,
                              hipStream_t stream) {
  const int* eidx = (const int*)d_in[18];

  char* ws = (char*)d_ws;
  size_t off = 0;
  auto alloc = [&](size_t bytes) -> char* {
    char* p = ws + off;
    off = (off + bytes + 255) & ~(size_t)255;
    return p;
  };

  bf16* xb   = (bf16*)alloc((size_t)NN * DD * 2);
  bf16* eb   = (bf16*)alloc((size_t)NE * DD * 2);
  bf16* eW0t = (bf16*)alloc((size_t)CW0 * 2);
  bf16* eW1t = (bf16*)alloc((size_t)CW1 * 2);
  bf16* eW2t = (bf16*)alloc((size_t)CW1 * 2);
  bf16* nW0t = (bf16*)alloc((size_t)CNW0 * 2);
  bf16* nW1t = (bf16*)alloc((size_t)CW1 * 2);
  bf16* nW2t = (bf16*)alloc((size_t)CW1 * 2);
  float* bf_[10];
  for (int i = 0; i < 10; i++) bf_[i] = (float*)alloc(CB * 4);
  int* counts = (int*)alloc((size_t)NN * 4);
  int* cursor = (int*)alloc((size_t)NN * 4);
  int* offs   = (int*)alloc((size_t)(NN + 1) * 4);
  int* sorted = (int*)alloc((size_t)NE * 4);
  int* flag   = (int*)alloc(4);

  // 1) zero counts + detect dtype
  detzero_kernel<<<80, 256, 0, stream>>>((const unsigned short*)d_in[0], counts, flag);

  // 2) all conversions in one kernel
  CvtP C;
  C.x = d_in[0]; C.e = d_in[1];
  C.w[0] = d_in[2];  C.w[1] = d_in[4];  C.w[2] = d_in[6];
  C.w[3] = d_in[10]; C.w[4] = d_in[12]; C.w[5] = d_in[14];
  C.xb = xb; C.eb = eb;
  C.wt[0] = eW0t; C.wt[1] = eW1t; C.wt[2] = eW2t;
  C.wt[3] = nW0t; C.wt[4] = nW1t; C.wt[5] = nW2t;
  const int bsrc_idx[10] = {3, 5, 7, 8, 9, 11, 13, 15, 16, 17};
  for (int i = 0; i < 10; i++) { C.bs[i] = d_in[bsrc_idx[i]]; C.bd[i] = bf_[i]; }
  C.flag = flag;
  convert_all<<<2048, 256, 0, stream>>>(C);

  // 3) CSR
  hist_kernel<<<(NE + 255) / 256, 256, 0, stream>>>(eidx, counts);
  scan_kernel<<<1, 1024, 0, stream>>>(counts, offs, cursor);
  fill_kernel<<<(NE + 255) / 256, 256, 0, stream>>>(eidx, offs, cursor, sorted);

  const int egrid = NE / 64;                // 1250 (MI=1: 64-row blocks)
  const int ngrid = (NN + 63) / 64;         // 313

  // 4) message passing: 2 dispatches per iteration (aggregate fused in node)
  for (int t = 0; t < NITER; t++) {
    fused_mlp<384, 1><<<egrid, 256, 0, stream>>>(
        xb, eb, eidx, nullptr, nullptr,
        eW0t + (size_t)t * 384 * DD, eW1t + (size_t)t * 128 * DD,
        eW2t + (size_t)t * 128 * DD,
        bf_[0] + t * DD, bf_[1] + t * DD, bf_[2] + t * DD,
        bf_[3] + t * DD, bf_[4] + t * DD, eb, NE);
    fused_mlp<256, 2><<<ngrid, 256, 0, stream>>>(
        xb, eb, nullptr, offs, sorted,
        nW0t + (size_t)t * 256 * DD, nW1t + (size_t)t * 128 * DD,
        nW2t + (size_t)t * 128 * DD,
        bf_[5] + t * DD, bf_[6] + t * DD, bf_[7] + t * DD,
        bf_[8] + t * DD, bf_[9] + t * DD, xb, NN);
  }

  // 5) output
  outwb_kernel<<<((NN + NE) * DD + 255) / 256, 256, 0, stream>>>(xb, eb, d_out, flag);
}

// Round 3
// 1535.402 us; speedup vs baseline: 1.9286x; 1.9286x over previous
//
#include <hip/hip_runtime.h>
#include <hip/hip_bf16.h>

typedef __hip_bfloat16 bf16;
typedef __attribute__((ext_vector_type(8))) short short8;
typedef __attribute__((ext_vector_type(4))) float f32x4;

#define NN 20000
#define NE 80000
#define DD 128
#define NITER 15
#define HSTRIDE 136   // 272 B row stride: 16B-aligned rows, 2-way LDS aliasing (free)

__device__ inline void gload16(const void* g, void* l) {
  __builtin_amdgcn_global_load_lds(
      (const __attribute__((address_space(1))) void*)g,
      (__attribute__((address_space(3))) void*)l, 16, 0, 0);
}

__device__ inline float bfbits2f(unsigned int hi16) {
  union { unsigned int u; float f; } c; c.u = hi16; return c.f;
}

__device__ inline float readin(const void* p, int i, int fl) {
  return fl ? (float)((const bf16*)p)[i] : ((const float*)p)[i];
}

// ---------------------------------------------------------------------------
// detzero: blocks 0..78 zero counts; block 79 runs dtype detection.
// flag = 1 -> bf16 inputs ; flag = 0 -> fp32 inputs.
// ---------------------------------------------------------------------------
__global__ void detzero_kernel(const unsigned short* __restrict__ x,
                               int* __restrict__ counts, int* __restrict__ flag) {
  const int bid = blockIdx.x, t = threadIdx.x;
  if (bid < 79) {
    int i = bid * 256 + t;
    if (i < NN) counts[i] = 0;
    return;
  }
  __shared__ int cs[256], ct[256];
  int sane = 0, tot = 0;
  for (int i = 2 * t; i < 16384; i += 512) {
    unsigned short v = x[i];
    int e = (v >> 7) & 0xFF;
    tot++;
    if (v == 0 || (e >= 80 && e <= 170)) sane++;
  }
  cs[t] = sane; ct[t] = tot;
  __syncthreads();
  for (int o = 128; o > 0; o >>= 1) {
    if (t < o) { cs[t] += cs[t + o]; ct[t] += ct[t + o]; }
    __syncthreads();
  }
  if (t == 0) *flag = (cs[0] * 10 > ct[0] * 7) ? 1 : 0;
}

// ---------------------------------------------------------------------------
// convert_all: one grid-stride kernel for every input canonicalization.
// ---------------------------------------------------------------------------
#define CX  (NN * DD)
#define CE  (NE * DD)
#define CW0 (NITER * 384 * DD)
#define CW1 (NITER * 128 * DD)
#define CNW0 (NITER * 256 * DD)
#define CB  (NITER * DD)
#define BX0 CX
#define BX1 (BX0 + CE)
#define BX7 (BX1 + CW0 + CW1 + CW1 + CNW0 + CW1 + CW1)
#define BX8 (BX7 + 10 * CB)

struct CvtP {
  const void *x, *e;
  const void* w[6];
  bf16 *xb, *eb;
  bf16* wt[6];
  const void* bs[10];
  float* bd[10];
  const int* flag;
};

__global__ void convert_all(CvtP P) {
  const int fl = *P.flag;
  const int gstride = gridDim.x * 256;
  for (int i = blockIdx.x * 256 + threadIdx.x; i < BX8; i += gstride) {
    if (i < BX0) {
      P.xb[i] = (bf16)readin(P.x, i, fl);
    } else if (i < BX1) {
      P.eb[i - BX0] = (bf16)readin(P.e, i - BX0, fl);
    } else if (i < BX7) {
      int j = i - BX1, w;
      if (j < CW0) { w = 0; }
      else if ((j -= CW0) < CW1) { w = 1; }
      else if ((j -= CW1) < CW1) { w = 2; }
      else if ((j -= CW1) < CNW0) { w = 3; }
      else if ((j -= CNW0) < CW1) { w = 4; }
      else { j -= CW1; w = 5; }
      const int K = (w == 0) ? 384 : (w == 3) ? 256 : 128;
      float v = readin(P.w[w], j, fl);
      int it = j / (K * DD);
      int rem = j - it * K * DD;
      int k = rem >> 7, n = rem & 127;
      P.wt[w][(size_t)it * K * DD + (size_t)n * K + k] = (bf16)v;
    } else {
      int j = i - BX7;
      int b = j / CB, r = j - b * CB;
      P.bd[b][r] = readin(P.bs[b], r, fl);
    }
  }
}

// ---------------------------------------------------------------------------
// Fused 3-layer MLP, 64-row x 128-col tile, 4 waves (16 rows each).
// PROVEN round-0 structure: B staged via double-buffered global_load_lds
// (one barrier per 32-K slab, DMA for slab s+1 in flight across slab s's
// compute); A direct-to-register 1-deep prefetch. LDS-free LayerNorm;
// bf16 residual state RMW (own rows).
// Rounds 1-2 lesson (measured): direct-B-from-global is 2-3x WORSE than
// this staged structure regardless of occupancy — do not remove staging.
//
// AMODE 1: A0 = concat(xb[row[m]], xb[col[m]], eb[m])  (K0=384)
//          LDS = 16K (B dbuf) + 17.4K (H) = 33.8 KB -> 4 blocks/CU.
// AMODE 2: A0 = concat(xb[m], agg[m]) with agg computed IN-KERNEL from CSR
//          into a wave-private LDS stripe (fuses old aggregate_kernel into
//          the node MLP's idle latency slots; node grid = 313 blocks =
//          1.2/CU, so CUs are idle there anyway). LDS = 51.2 KB -> 3/CU
//          (irrelevant at this grid size). Verified correct in round 2.
// ---------------------------------------------------------------------------
template<int K0, int AMODE>
__global__ __launch_bounds__(256, 4) void fused_mlp(
    const bf16* S0b,                 // xb (aliases st for AMODE 2)
    const bf16* S1b,                 // eb (AMODE 1: A seg2, aliases st; AMODE 2: agg source)
    const int*  __restrict__ eidx,
    const int*  __restrict__ offs,   // AMODE 2 only (CSR)
    const int*  __restrict__ sorted, // AMODE 2 only (CSR)
    const bf16* __restrict__ W0t, const bf16* __restrict__ W1t,
    const bf16* __restrict__ W2t,
    const float* __restrict__ b0, const float* __restrict__ b1,
    const float* __restrict__ b2,
    const float* __restrict__ gamma, const float* __restrict__ beta,
    bf16* st, int M)
{
  constexpr int NS1 = K0 / 32;       // 12 or 8 (even)
  __shared__ __align__(16) bf16 Bls[2][128 * 32];
  __shared__ __align__(16) bf16 Hls[64 * HSTRIDE];
  __shared__ __align__(16) bf16 Als[(AMODE == 2) ? 64 * HSTRIDE : 16];

  const int tid  = threadIdx.x;
  const int lane = tid & 63;
  const int wv   = tid >> 6;
  const int l15  = lane & 15, quad = lane >> 4;
  const int m0   = blockIdx.x * 64;
  const int scol = tid >> 2;
  const int sk8  = (tid & 3) * 8;

  const int rowm = min(m0 + wv * 16 + l15, M - 1);
  int ir = 0, ic = 0;
  if (AMODE == 1) { ir = eidx[rowm]; ic = eidx[NE + rowm]; }

  // ---- AMODE 2 prologue: CSR aggregate into wave-private LDS rows --------
  if (AMODE == 2) {
    for (int g = 0; g < 16; ++g) {
      const int node = min(m0 + wv * 16 + g, M - 1);
      const int s = offs[node], t = offs[node + 1];
      float a0 = 0.f, a1 = 0.f;
      for (int i = s; i < t; i++) {
        const int e = sorted[i];
        unsigned int v = *(const unsigned int*)(S1b + (size_t)e * DD + 2 * lane);
        a0 += bfbits2f(v << 16);
        a1 += bfbits2f(v & 0xFFFF0000u);
      }
      bf16 o0 = (bf16)a0, o1 = (bf16)a1;
      unsigned int pack = (unsigned int)(*(unsigned short*)&o0)
                        | ((unsigned int)(*(unsigned short*)&o1) << 16);
      *(unsigned int*)&Als[(wv * 16 + g) * HSTRIDE + 2 * lane] = pack;
    }
  }

  auto dmaW = [&](const bf16* W, int K, int kk, int buf) {
    gload16(W + (size_t)scol * K + kk + sk8,        &Bls[buf][scol * 32 + sk8]);
    gload16(W + (size_t)(scol + 64) * K + kk + sk8, &Bls[buf][(scol + 64) * 32 + sk8]);
  };
  auto gatherA = [&](int kk, short8* a) {
    const int ks = (kk & 127) + quad * 8;
    if (AMODE == 1) {
      const int seg = kk >> 7;
      const bf16* base = (seg == 0) ? S0b + (size_t)ir * DD
                       : (seg == 1) ? S0b + (size_t)ic * DD
                                    : S1b + (size_t)rowm * DD;
      *a = *(const short8*)(base + ks);
    } else {
      if (kk >> 7) *a = *(const short8*)&Als[(wv * 16 + l15) * HSTRIDE + ks];
      else         *a = *(const short8*)(S0b + (size_t)rowm * DD + ks);
    }
  };

  f32x4 acc[8];
  auto zacc = [&]() {
#pragma unroll
    for (int j = 0; j < 8; j++) acc[j] = (f32x4){0.f, 0.f, 0.f, 0.f};
  };
  auto slabMfmaA = [&](short8 a, int buf) {
    short8 bfr[8];
#pragma unroll
    for (int ni = 0; ni < 8; ni++)
      bfr[ni] = *(const short8*)&Bls[buf][(ni * 16 + l15) * 32 + quad * 8];
#pragma unroll
    for (int ni = 0; ni < 8; ni++)
      acc[ni] = __builtin_amdgcn_mfma_f32_16x16x32_bf16(a, bfr[ni], acc[ni], 0, 0, 0);
  };
  auto slabMfmaH = [&](int kk, int buf) {
    short8 a = *(const short8*)&Hls[(wv * 16 + l15) * HSTRIDE + kk + quad * 8];
    short8 bfr[8];
#pragma unroll
    for (int ni = 0; ni < 8; ni++)
      bfr[ni] = *(const short8*)&Bls[buf][(ni * 16 + l15) * 32 + quad * 8];
#pragma unroll
    for (int ni = 0; ni < 8; ni++)
      acc[ni] = __builtin_amdgcn_mfma_f32_16x16x32_bf16(a, bfr[ni], acc[ni], 0, 0, 0);
  };
  auto writeH = [&](const float* bias) {
    float bv[8];
#pragma unroll
    for (int ni = 0; ni < 8; ni++) bv[ni] = bias[ni * 16 + l15];
#pragma unroll
    for (int r = 0; r < 4; r++) {
      const int row = wv * 16 + quad * 4 + r;
#pragma unroll
      for (int ni = 0; ni < 8; ni++)
        Hls[row * HSTRIDE + ni * 16 + l15] = (bf16)fmaxf(acc[ni][r] + bv[ni], 0.f);
    }
  };

  // Phase 1
  zacc();
  short8 aCur, aNxt;
  dmaW(W0t, K0, 0, 0);
  gatherA(0, &aCur);
  __syncthreads();
#pragma unroll
  for (int s = 0; s < NS1; s++) {
    if (s + 1 < NS1) {
      dmaW(W0t, K0, (s + 1) * 32, (s + 1) & 1);
      gatherA((s + 1) * 32, &aNxt);
    } else {
      dmaW(W1t, 128, 0, NS1 & 1);
    }
    slabMfmaA(aCur, s & 1);
    __syncthreads();
    aCur = aNxt;
  }
  writeH(b0);
  __syncthreads();

  // Phase 2
  zacc();
#pragma unroll
  for (int s = 0; s < 4; s++) {
    if (s < 3) dmaW(W1t, 128, (s + 1) * 32, (NS1 + s + 1) & 1);
    else       dmaW(W2t, 128, 0,            (NS1 + 4) & 1);
    slabMfmaH(s * 32, (NS1 + s) & 1);
    __syncthreads();
  }
  writeH(b1);
  __syncthreads();

  // Phase 3 + LN + residual
  zacc();
#pragma unroll
  for (int s = 0; s < 4; s++) {
    if (s < 3) dmaW(W2t, 128, (s + 1) * 32, (NS1 + 4 + s + 1) & 1);
    slabMfmaH(s * 32, (NS1 + 4 + s) & 1);
    if (s < 3) __syncthreads();
  }

  float bv[8], gv[8], btv[8];
#pragma unroll
  for (int ni = 0; ni < 8; ni++) {
    const int col = ni * 16 + l15;
    bv[ni] = b2[col]; gv[ni] = gamma[col]; btv[ni] = beta[col];
  }
#pragma unroll
  for (int r = 0; r < 4; r++) {
    float a = 0.f, bq = 0.f;
#pragma unroll
    for (int ni = 0; ni < 8; ni++) {
      const float v = acc[ni][r] + bv[ni];
      a += v; bq += v * v;
    }
#pragma unroll
    for (int off = 1; off < 16; off <<= 1) {
      a  += __shfl_xor(a, off);
      bq += __shfl_xor(bq, off);
    }
    const float mu = a * (1.0f / 128.0f);
    const float var = fmaxf(bq * (1.0f / 128.0f) - mu * mu, 0.0f);
    const float rs = rsqrtf(var + 1e-5f);
    const int m = m0 + wv * 16 + quad * 4 + r;
    if (m < M) {
#pragma unroll
      for (int ni = 0; ni < 8; ni++) {
        const int col = ni * 16 + l15;
        const float v = acc[ni][r] + bv[ni];
        const float lnv = (v - mu) * rs * gv[ni] + btv[ni];
        const size_t idx = (size_t)m * DD + col;
        st[idx] = (bf16)(lnv + (float)st[idx]);
      }
    }
  }
}

// --------------------------- CSR build ------------------------------------
__global__ void hist_kernel(const int* __restrict__ eidx, int* __restrict__ counts) {
  int e = blockIdx.x * 256 + threadIdx.x;
  if (e < NE) atomicAdd(&counts[eidx[NE + e]], 1);
}

__global__ void scan_kernel(const int* __restrict__ counts, int* __restrict__ offs,
                            int* __restrict__ cursor) {
  __shared__ int sums[1024];
  const int t = threadIdx.x;
  const int base = t * 20;
  int local[20];
  int s = 0;
  for (int i = 0; i < 20; i++) {
    int idx = base + i;
    int c = (idx < NN) ? counts[idx] : 0;
    local[i] = s; s += c;
  }
  sums[t] = s;
  __syncthreads();
  for (int off = 1; off < 1024; off <<= 1) {
    int v = 0;
    if (t >= off) v = sums[t - off];
    __syncthreads();
    if (t >= off) sums[t] += v;
    __syncthreads();
  }
  int excl = (t == 0) ? 0 : sums[t - 1];
  for (int i = 0; i < 20; i++) {
    int idx = base + i;
    if (idx < NN) { offs[idx] = excl + local[i]; cursor[idx] = 0; }
  }
  if (t == 1023) offs[NN] = sums[1023];
}

__global__ void fill_kernel(const int* __restrict__ eidx, const int* __restrict__ offs,
                            int* __restrict__ cursor, int* __restrict__ sorted) {
  int e = blockIdx.x * 256 + threadIdx.x;
  if (e < NE) {
    int n = eidx[NE + e];
    int p = atomicAdd(&cursor[n], 1);
    sorted[offs[n] + p] = e;
  }
}

// bf16 states -> d_out in detected dtype
__global__ void outwb_kernel(const bf16* __restrict__ xb, const bf16* __restrict__ eb,
                             void* __restrict__ out, const int* __restrict__ flag) {
  int i = blockIdx.x * 256 + threadIdx.x;
  const int nx = NN * DD, total = (NN + NE) * DD;
  if (i < total) {
    bf16 v = (i < nx) ? xb[i] : eb[i - nx];
    if (*flag) ((bf16*)out)[i] = v;
    else       ((float*)out)[i] = (float)v;
  }
}

// ---------------------------------------------------------------------------
extern "C" void kernel_launch(void* const* d_in, const int* in_sizes, int n_in,
                              void* d_out, int out_size, void* d_ws, size_t ws_size,
                              hipStream_t stream) {
  const int* eidx = (const int*)d_in[18];

  char* ws = (char*)d_ws;
  size_t off = 0;
  auto alloc = [&](size_t bytes) -> char* {
    char* p = ws + off;
    off = (off + bytes + 255) & ~(size_t)255;
    return p;
  };

  bf16* xb   = (bf16*)alloc((size_t)NN * DD * 2);
  bf16* eb   = (bf16*)alloc((size_t)NE * DD * 2);
  bf16* eW0t = (bf16*)alloc((size_t)CW0 * 2);
  bf16* eW1t = (bf16*)alloc((size_t)CW1 * 2);
  bf16* eW2t = (bf16*)alloc((size_t)CW1 * 2);
  bf16* nW0t = (bf16*)alloc((size_t)CNW0 * 2);
  bf16* nW1t = (bf16*)alloc((size_t)CW1 * 2);
  bf16* nW2t = (bf16*)alloc((size_t)CW1 * 2);
  float* bf_[10];
  for (int i = 0; i < 10; i++) bf_[i] = (float*)alloc(CB * 4);
  int* counts = (int*)alloc((size_t)NN * 4);
  int* cursor = (int*)alloc((size_t)NN * 4);
  int* offs   = (int*)alloc((size_t)(NN + 1) * 4);
  int* sorted = (int*)alloc((size_t)NE * 4);
  int* flag   = (int*)alloc(4);

  // 1) zero counts + detect dtype
  detzero_kernel<<<80, 256, 0, stream>>>((const unsigned short*)d_in[0], counts, flag);

  // 2) all conversions in one kernel
  CvtP C;
  C.x = d_in[0]; C.e = d_in[1];
  C.w[0] = d_in[2];  C.w[1] = d_in[4];  C.w[2] = d_in[6];
  C.w[3] = d_in[10]; C.w[4] = d_in[12]; C.w[5] = d_in[14];
  C.xb = xb; C.eb = eb;
  C.wt[0] = eW0t; C.wt[1] = eW1t; C.wt[2] = eW2t;
  C.wt[3] = nW0t; C.wt[4] = nW1t; C.wt[5] = nW2t;
  const int bsrc_idx[10] = {3, 5, 7, 8, 9, 11, 13, 15, 16, 17};
  for (int i = 0; i < 10; i++) { C.bs[i] = d_in[bsrc_idx[i]]; C.bd[i] = bf_[i]; }
  C.flag = flag;
  convert_all<<<2048, 256, 0, stream>>>(C);

  // 3) CSR
  hist_kernel<<<(NE + 255) / 256, 256, 0, stream>>>(eidx, counts);
  scan_kernel<<<1, 1024, 0, stream>>>(counts, offs, cursor);
  fill_kernel<<<(NE + 255) / 256, 256, 0, stream>>>(eidx, offs, cursor, sorted);

  const int egrid = NE / 64;                // 1250 (4 blocks/CU by LDS)
  const int ngrid = (NN + 63) / 64;         // 313

  // 4) message passing: 2 dispatches per iteration (aggregate fused in node)
  for (int t = 0; t < NITER; t++) {
    fused_mlp<384, 1><<<egrid, 256, 0, stream>>>(
        xb, eb, eidx, nullptr, nullptr,
        eW0t + (size_t)t * 384 * DD, eW1t + (size_t)t * 128 * DD,
        eW2t + (size_t)t * 128 * DD,
        bf_[0] + t * DD, bf_[1] + t * DD, bf_[2] + t * DD,
        bf_[3] + t * DD, bf_[4] + t * DD, eb, NE);
    fused_mlp<256, 2><<<ngrid, 256, 0, stream>>>(
        xb, eb, nullptr, offs, sorted,
        nW0t + (size_t)t * 256 * DD, nW1t + (size_t)t * 128 * DD,
        nW2t + (size_t)t * 128 * DD,
        bf_[5] + t * DD, bf_[6] + t * DD, bf_[7] + t * DD,
        bf_[8] + t * DD, bf_[9] + t * DD, xb, NN);
  }

  // 5) output
  outwb_kernel<<<((NN + NE) * DD + 255) / 256, 256, 0, stream>>>(xb, eb, d_out, flag);
}

// Round 4
// 1130.753 us; speedup vs baseline: 2.6188x; 1.3579x over previous
//
#include <hip/hip_runtime.h>
#include <hip/hip_bf16.h>

typedef __hip_bfloat16 bf16;
typedef __attribute__((ext_vector_type(8))) short short8;
typedef __attribute__((ext_vector_type(4))) float f32x4;

#define NN 20000
#define NE 80000
#define DD 128
#define NITER 15
#define HSTRIDE 136   // 272 B row stride: 16B-aligned rows, 2-way LDS aliasing (free)

__device__ inline void gload16(const void* g, void* l) {
  __builtin_amdgcn_global_load_lds(
      (const __attribute__((address_space(1))) void*)g,
      (__attribute__((address_space(3))) void*)l, 16, 0, 0);
}

__device__ inline float bfbits2f(unsigned int hi16) {
  union { unsigned int u; float f; } c; c.u = hi16; return c.f;
}

__device__ inline float readin(const void* p, int i, int fl) {
  return fl ? (float)((const bf16*)p)[i] : ((const float*)p)[i];
}

// ---------------------------------------------------------------------------
// detzero: blocks 0..78 zero counts; block 79 runs dtype detection.
// flag = 1 -> bf16 inputs ; flag = 0 -> fp32 inputs.
// ---------------------------------------------------------------------------
__global__ void detzero_kernel(const unsigned short* __restrict__ x,
                               int* __restrict__ counts, int* __restrict__ flag) {
  const int bid = blockIdx.x, t = threadIdx.x;
  if (bid < 79) {
    int i = bid * 256 + t;
    if (i < NN) counts[i] = 0;
    return;
  }
  __shared__ int cs[256], ct[256];
  int sane = 0, tot = 0;
  for (int i = 2 * t; i < 16384; i += 512) {
    unsigned short v = x[i];
    int e = (v >> 7) & 0xFF;
    tot++;
    if (v == 0 || (e >= 80 && e <= 170)) sane++;
  }
  cs[t] = sane; ct[t] = tot;
  __syncthreads();
  for (int o = 128; o > 0; o >>= 1) {
    if (t < o) { cs[t] += cs[t + o]; ct[t] += ct[t + o]; }
    __syncthreads();
  }
  if (t == 0) *flag = (cs[0] * 10 > ct[0] * 7) ? 1 : 0;
}

// ---------------------------------------------------------------------------
// convert_all: one grid-stride kernel for every input canonicalization.
// ---------------------------------------------------------------------------
#define CX  (NN * DD)
#define CE  (NE * DD)
#define CW0 (NITER * 384 * DD)
#define CW1 (NITER * 128 * DD)
#define CNW0 (NITER * 256 * DD)
#define CB  (NITER * DD)
#define BX0 CX
#define BX1 (BX0 + CE)
#define BX7 (BX1 + CW0 + CW1 + CW1 + CNW0 + CW1 + CW1)
#define BX8 (BX7 + 10 * CB)

struct CvtP {
  const void *x, *e;
  const void* w[6];
  bf16 *xb, *eb;
  bf16* wt[6];
  const void* bs[10];
  float* bd[10];
  const int* flag;
};

__global__ void convert_all(CvtP P) {
  const int fl = *P.flag;
  const int gstride = gridDim.x * 256;
  for (int i = blockIdx.x * 256 + threadIdx.x; i < BX8; i += gstride) {
    if (i < BX0) {
      P.xb[i] = (bf16)readin(P.x, i, fl);
    } else if (i < BX1) {
      P.eb[i - BX0] = (bf16)readin(P.e, i - BX0, fl);
    } else if (i < BX7) {
      int j = i - BX1, w;
      if (j < CW0) { w = 0; }
      else if ((j -= CW0) < CW1) { w = 1; }
      else if ((j -= CW1) < CW1) { w = 2; }
      else if ((j -= CW1) < CNW0) { w = 3; }
      else if ((j -= CNW0) < CW1) { w = 4; }
      else { j -= CW1; w = 5; }
      const int K = (w == 0) ? 384 : (w == 3) ? 256 : 128;
      float v = readin(P.w[w], j, fl);
      int it = j / (K * DD);
      int rem = j - it * K * DD;
      int k = rem >> 7, n = rem & 127;
      P.wt[w][(size_t)it * K * DD + (size_t)n * K + k] = (bf16)v;
    } else {
      int j = i - BX7;
      int b = j / CB, r = j - b * CB;
      P.bd[b][r] = readin(P.bs[b], r, fl);
    }
  }
}

// ---------------------------------------------------------------------------
// Fused 3-layer MLP, NW waves (16 rows each), 128-col tile.
// PROVEN round-0 staging: B double-buffered via global_load_lds (one barrier
// per 32-K slab, DMA for slab s+1 in flight across slab s's compute);
// A direct-to-register 1-deep prefetch; LDS-free LayerNorm; bf16 residual.
//
// Round-3 lesson (measured): fusing the CSR aggregate into this kernel's
// prologue costs +44 us (serial gather at 1.2 blocks/CU) — aggregate stays
// a separate fat-grid kernel. Rounds 1-2 lesson: direct-B-from-global is
// 2-3x worse than staging — keep staging.
//
// NW=8 (edge): 128-row blocks, 625 blocks. Halves per-CU barrier-drain
//   count and weight L2 refetch vs 64-row; 3 blocks/CU (LDS 51.2K) = 24
//   resident waves. DMA = 1 gload16/thread (512 x 16B = 8KB slab, dest
//   byte offset = 16*tid — lane-linear, valid for global_load_lds).
// NW=4 (node): round-0 proven 64-row config, 313 blocks, 4 blocks/CU.
//
// AMODE 1: A0 = concat(xb[row[m]], xb[col[m]], eb[m])  (K0=384)
// AMODE 2: A0 = concat(xb[m], aggb[m])                 (K0=256)
// ---------------------------------------------------------------------------
template<int K0, int AMODE, int NW>
__global__ __launch_bounds__(NW * 64, NW == 8 ? 6 : 4) void fused_mlp(
    const bf16* S0b,                 // xb (may alias st for AMODE 2)
    const bf16* S1b,                 // eb (AMODE 1, aliases st) / aggb (AMODE 2)
    const int*  __restrict__ eidx,
    const bf16* __restrict__ W0t, const bf16* __restrict__ W1t,
    const bf16* __restrict__ W2t,
    const float* __restrict__ b0, const float* __restrict__ b1,
    const float* __restrict__ b2,
    const float* __restrict__ gamma, const float* __restrict__ beta,
    bf16* st, int M)
{
  constexpr int NS1  = K0 / 32;      // 12 or 8 (even)
  constexpr int ROWS = NW * 16;
  __shared__ __align__(16) bf16 Bls[2][128 * 32];
  __shared__ __align__(16) bf16 Hls[ROWS * HSTRIDE];

  const int tid  = threadIdx.x;
  const int lane = tid & 63;
  const int wv   = tid >> 6;
  const int l15  = lane & 15, quad = lane >> 4;
  const int m0   = blockIdx.x * ROWS;
  const int scol = tid >> 2;
  const int sk8  = (tid & 3) * 8;

  const int rowm = min(m0 + wv * 16 + l15, M - 1);
  int ir = 0, ic = 0;
  if (AMODE == 1) { ir = eidx[rowm]; ic = eidx[NE + rowm]; }

  auto dmaW = [&](const bf16* W, int K, int kk, int buf) {
    gload16(W + (size_t)scol * K + kk + sk8, &Bls[buf][scol * 32 + sk8]);
    if (NW == 4)
      gload16(W + (size_t)(scol + 64) * K + kk + sk8, &Bls[buf][(scol + 64) * 32 + sk8]);
  };
  auto gatherA = [&](int kk, short8* a) {
    const int ks = (kk & 127) + quad * 8;
    const bf16* base;
    if (AMODE == 1) {
      const int seg = kk >> 7;
      base = (seg == 0) ? S0b + (size_t)ir * DD
           : (seg == 1) ? S0b + (size_t)ic * DD
                        : S1b + (size_t)rowm * DD;
    } else {
      base = (kk >> 7) ? S1b + (size_t)rowm * DD
                       : S0b + (size_t)rowm * DD;
    }
    *a = *(const short8*)(base + ks);
  };

  f32x4 acc[8];
  auto zacc = [&]() {
#pragma unroll
    for (int j = 0; j < 8; j++) acc[j] = (f32x4){0.f, 0.f, 0.f, 0.f};
  };
  auto slabMfmaA = [&](short8 a, int buf) {
    short8 bfr[8];
#pragma unroll
    for (int ni = 0; ni < 8; ni++)
      bfr[ni] = *(const short8*)&Bls[buf][(ni * 16 + l15) * 32 + quad * 8];
#pragma unroll
    for (int ni = 0; ni < 8; ni++)
      acc[ni] = __builtin_amdgcn_mfma_f32_16x16x32_bf16(a, bfr[ni], acc[ni], 0, 0, 0);
  };
  auto slabMfmaH = [&](int kk, int buf) {
    short8 a = *(const short8*)&Hls[(wv * 16 + l15) * HSTRIDE + kk + quad * 8];
    short8 bfr[8];
#pragma unroll
    for (int ni = 0; ni < 8; ni++)
      bfr[ni] = *(const short8*)&Bls[buf][(ni * 16 + l15) * 32 + quad * 8];
#pragma unroll
    for (int ni = 0; ni < 8; ni++)
      acc[ni] = __builtin_amdgcn_mfma_f32_16x16x32_bf16(a, bfr[ni], acc[ni], 0, 0, 0);
  };
  auto writeH = [&](const float* bias) {
    float bv[8];
#pragma unroll
    for (int ni = 0; ni < 8; ni++) bv[ni] = bias[ni * 16 + l15];
#pragma unroll
    for (int r = 0; r < 4; r++) {
      const int row = wv * 16 + quad * 4 + r;
#pragma unroll
      for (int ni = 0; ni < 8; ni++)
        Hls[row * HSTRIDE + ni * 16 + l15] = (bf16)fmaxf(acc[ni][r] + bv[ni], 0.f);
    }
  };

  // Phase 1
  zacc();
  short8 aCur, aNxt;
  dmaW(W0t, K0, 0, 0);
  gatherA(0, &aCur);
  __syncthreads();
#pragma unroll
  for (int s = 0; s < NS1; s++) {
    if (s + 1 < NS1) {
      dmaW(W0t, K0, (s + 1) * 32, (s + 1) & 1);
      gatherA((s + 1) * 32, &aNxt);
    } else {
      dmaW(W1t, 128, 0, NS1 & 1);
    }
    slabMfmaA(aCur, s & 1);
    __syncthreads();
    aCur = aNxt;
  }
  writeH(b0);
  __syncthreads();

  // Phase 2
  zacc();
#pragma unroll
  for (int s = 0; s < 4; s++) {
    if (s < 3) dmaW(W1t, 128, (s + 1) * 32, (NS1 + s + 1) & 1);
    else       dmaW(W2t, 128, 0,            (NS1 + 4) & 1);
    slabMfmaH(s * 32, (NS1 + s) & 1);
    __syncthreads();
  }
  writeH(b1);
  __syncthreads();

  // Phase 3 + LN + residual
  zacc();
#pragma unroll
  for (int s = 0; s < 4; s++) {
    if (s < 3) dmaW(W2t, 128, (s + 1) * 32, (NS1 + 4 + s + 1) & 1);
    slabMfmaH(s * 32, (NS1 + 4 + s) & 1);
    if (s < 3) __syncthreads();
  }

  float bv[8], gv[8], btv[8];
#pragma unroll
  for (int ni = 0; ni < 8; ni++) {
    const int col = ni * 16 + l15;
    bv[ni] = b2[col]; gv[ni] = gamma[col]; btv[ni] = beta[col];
  }
#pragma unroll
  for (int r = 0; r < 4; r++) {
    float a = 0.f, bq = 0.f;
#pragma unroll
    for (int ni = 0; ni < 8; ni++) {
      const float v = acc[ni][r] + bv[ni];
      a += v; bq += v * v;
    }
#pragma unroll
    for (int off = 1; off < 16; off <<= 1) {
      a  += __shfl_xor(a, off);
      bq += __shfl_xor(bq, off);
    }
    const float mu = a * (1.0f / 128.0f);
    const float var = fmaxf(bq * (1.0f / 128.0f) - mu * mu, 0.0f);
    const float rs = rsqrtf(var + 1e-5f);
    const int m = m0 + wv * 16 + quad * 4 + r;
    if (m < M) {
#pragma unroll
      for (int ni = 0; ni < 8; ni++) {
        const int col = ni * 16 + l15;
        const float v = acc[ni][r] + bv[ni];
        const float lnv = (v - mu) * rs * gv[ni] + btv[ni];
        const size_t idx = (size_t)m * DD + col;
        st[idx] = (bf16)(lnv + (float)st[idx]);
      }
    }
  }
}

// --------------------------- CSR build + aggregate -------------------------
__global__ void hist_kernel(const int* __restrict__ eidx, int* __restrict__ counts) {
  int e = blockIdx.x * 256 + threadIdx.x;
  if (e < NE) atomicAdd(&counts[eidx[NE + e]], 1);
}

__global__ void scan_kernel(const int* __restrict__ counts, int* __restrict__ offs,
                            int* __restrict__ cursor) {
  __shared__ int sums[1024];
  const int t = threadIdx.x;
  const int base = t * 20;
  int local[20];
  int s = 0;
  for (int i = 0; i < 20; i++) {
    int idx = base + i;
    int c = (idx < NN) ? counts[idx] : 0;
    local[i] = s; s += c;
  }
  sums[t] = s;
  __syncthreads();
  for (int off = 1; off < 1024; off <<= 1) {
    int v = 0;
    if (t >= off) v = sums[t - off];
    __syncthreads();
    if (t >= off) sums[t] += v;
    __syncthreads();
  }
  int excl = (t == 0) ? 0 : sums[t - 1];
  for (int i = 0; i < 20; i++) {
    int idx = base + i;
    if (idx < NN) { offs[idx] = excl + local[i]; cursor[idx] = 0; }
  }
  if (t == 1023) offs[NN] = sums[1023];
}

__global__ void fill_kernel(const int* __restrict__ eidx, const int* __restrict__ offs,
                            int* __restrict__ cursor, int* __restrict__ sorted) {
  int e = blockIdx.x * 256 + threadIdx.x;
  if (e < NE) {
    int n = eidx[NE + e];
    int p = atomicAdd(&cursor[n], 1);
    sorted[offs[n] + p] = e;
  }
}

// wave per node (fat grid: 20000 waves, 32 waves/CU -> latency well hidden):
// packed-uint bf16x2 loads, fp32 sums, bf16 out.
__global__ void aggregate_kernel(const bf16* __restrict__ eb, const int* __restrict__ offs,
                                 const int* __restrict__ sorted, bf16* __restrict__ aggb) {
  const int node = blockIdx.x * 4 + (threadIdx.x >> 6);
  const int lane = threadIdx.x & 63;
  if (node >= NN) return;
  const int s = offs[node], t = offs[node + 1];
  float a0 = 0.f, a1 = 0.f;
  for (int i = s; i < t; i++) {
    const int e = sorted[i];
    unsigned int v = *(const unsigned int*)(eb + (size_t)e * DD + 2 * lane);
    a0 += bfbits2f(v << 16);
    a1 += bfbits2f(v & 0xFFFF0000u);
  }
  bf16 o0 = (bf16)a0, o1 = (bf16)a1;
  unsigned int pack = (unsigned int)(*(unsigned short*)&o0)
                    | ((unsigned int)(*(unsigned short*)&o1) << 16);
  *(unsigned int*)(aggb + (size_t)node * DD + 2 * lane) = pack;
}

// bf16 states -> d_out in detected dtype
__global__ void outwb_kernel(const bf16* __restrict__ xb, const bf16* __restrict__ eb,
                             void* __restrict__ out, const int* __restrict__ flag) {
  int i = blockIdx.x * 256 + threadIdx.x;
  const int nx = NN * DD, total = (NN + NE) * DD;
  if (i < total) {
    bf16 v = (i < nx) ? xb[i] : eb[i - nx];
    if (*flag) ((bf16*)out)[i] = v;
    else       ((float*)out)[i] = (float)v;
  }
}

// ---------------------------------------------------------------------------
extern "C" void kernel_launch(void* const* d_in, const int* in_sizes, int n_in,
                              void* d_out, int out_size, void* d_ws, size_t ws_size,
                              hipStream_t stream) {
  const int* eidx = (const int*)d_in[18];

  char* ws = (char*)d_ws;
  size_t off = 0;
  auto alloc = [&](size_t bytes) -> char* {
    char* p = ws + off;
    off = (off + bytes + 255) & ~(size_t)255;
    return p;
  };

  bf16* xb   = (bf16*)alloc((size_t)NN * DD * 2);
  bf16* eb   = (bf16*)alloc((size_t)NE * DD * 2);
  bf16* aggb = (bf16*)alloc((size_t)NN * DD * 2);
  bf16* eW0t = (bf16*)alloc((size_t)CW0 * 2);
  bf16* eW1t = (bf16*)alloc((size_t)CW1 * 2);
  bf16* eW2t = (bf16*)alloc((size_t)CW1 * 2);
  bf16* nW0t = (bf16*)alloc((size_t)CNW0 * 2);
  bf16* nW1t = (bf16*)alloc((size_t)CW1 * 2);
  bf16* nW2t = (bf16*)alloc((size_t)CW1 * 2);
  float* bf_[10];
  for (int i = 0; i < 10; i++) bf_[i] = (float*)alloc(CB * 4);
  int* counts = (int*)alloc((size_t)NN * 4);
  int* cursor = (int*)alloc((size_t)NN * 4);
  int* offs   = (int*)alloc((size_t)(NN + 1) * 4);
  int* sorted = (int*)alloc((size_t)NE * 4);
  int* flag   = (int*)alloc(4);

  // 1) zero counts + detect dtype
  detzero_kernel<<<80, 256, 0, stream>>>((const unsigned short*)d_in[0], counts, flag);

  // 2) all conversions in one kernel
  CvtP C;
  C.x = d_in[0]; C.e = d_in[1];
  C.w[0] = d_in[2];  C.w[1] = d_in[4];  C.w[2] = d_in[6];
  C.w[3] = d_in[10]; C.w[4] = d_in[12]; C.w[5] = d_in[14];
  C.xb = xb; C.eb = eb;
  C.wt[0] = eW0t; C.wt[1] = eW1t; C.wt[2] = eW2t;
  C.wt[3] = nW0t; C.wt[4] = nW1t; C.wt[5] = nW2t;
  const int bsrc_idx[10] = {3, 5, 7, 8, 9, 11, 13, 15, 16, 17};
  for (int i = 0; i < 10; i++) { C.bs[i] = d_in[bsrc_idx[i]]; C.bd[i] = bf_[i]; }
  C.flag = flag;
  convert_all<<<2048, 256, 0, stream>>>(C);

  // 3) CSR
  hist_kernel<<<(NE + 255) / 256, 256, 0, stream>>>(eidx, counts);
  scan_kernel<<<1, 1024, 0, stream>>>(counts, offs, cursor);
  fill_kernel<<<(NE + 255) / 256, 256, 0, stream>>>(eidx, offs, cursor, sorted);

  const int egrid = NE / 128;               // 625 (8-wave, 128-row blocks)
  const int ngrid = (NN + 63) / 64;         // 313 (4-wave, 64-row blocks)

  // 4) message passing: 3 dispatches per iteration
  for (int t = 0; t < NITER; t++) {
    fused_mlp<384, 1, 8><<<egrid, 512, 0, stream>>>(
        xb, eb, eidx,
        eW0t + (size_t)t * 384 * DD, eW1t + (size_t)t * 128 * DD,
        eW2t + (size_t)t * 128 * DD,
        bf_[0] + t * DD, bf_[1] + t * DD, bf_[2] + t * DD,
        bf_[3] + t * DD, bf_[4] + t * DD, eb, NE);
    aggregate_kernel<<<(NN + 3) / 4, 256, 0, stream>>>(eb, offs, sorted, aggb);
    fused_mlp<256, 2, 4><<<ngrid, 256, 0, stream>>>(
        xb, aggb, nullptr,
        nW0t + (size_t)t * 256 * DD, nW1t + (size_t)t * 128 * DD,
        nW2t + (size_t)t * 128 * DD,
        bf_[5] + t * DD, bf_[6] + t * DD, bf_[7] + t * DD,
        bf_[8] + t * DD, bf_[9] + t * DD, xb, NN);
  }

  // 5) output
  outwb_kernel<<<((NN + NE) * DD + 255) / 256, 256, 0, stream>>>(xb, eb, d_out, flag);
}

// Round 5
// 1097.890 us; speedup vs baseline: 2.6972x; 1.0299x over previous
//
#include <hip/hip_runtime.h>
#include <hip/hip_bf16.h>

typedef __hip_bfloat16 bf16;
typedef __attribute__((ext_vector_type(8))) short short8;
typedef __attribute__((ext_vector_type(4))) float f32x4;

#define NN 20000
#define NE 80000
#define DD 128
#define NITER 15
#define HSTRIDE 136   // 272 B row stride: 16B-aligned rows, 2-way LDS aliasing (free)

__device__ inline void gload16(const void* g, void* l) {
  __builtin_amdgcn_global_load_lds(
      (const __attribute__((address_space(1))) void*)g,
      (__attribute__((address_space(3))) void*)l, 16, 0, 0);
}

// counted vmem wait: allow exactly n newest vector-memory ops to stay in
// flight; everything older (the slab we're about to consume) must land.
__device__ inline void waitVm(int n) {
  switch (n) {
    case 0: asm volatile("s_waitcnt vmcnt(0)" ::: "memory"); break;
    case 1: asm volatile("s_waitcnt vmcnt(1)" ::: "memory"); break;
    case 2: asm volatile("s_waitcnt vmcnt(2)" ::: "memory"); break;
    case 3: asm volatile("s_waitcnt vmcnt(3)" ::: "memory"); break;
    default: asm volatile("s_waitcnt vmcnt(4)" ::: "memory"); break;
  }
}

__device__ inline float bfbits2f(unsigned int hi16) {
  union { unsigned int u; float f; } c; c.u = hi16; return c.f;
}

__device__ inline float readin(const void* p, int i, int fl) {
  return fl ? (float)((const bf16*)p)[i] : ((const float*)p)[i];
}

// ---------------------------------------------------------------------------
// detzero: blocks 0..78 zero counts; block 79 runs dtype detection.
// flag = 1 -> bf16 inputs ; flag = 0 -> fp32 inputs.
// ---------------------------------------------------------------------------
__global__ void detzero_kernel(const unsigned short* __restrict__ x,
                               int* __restrict__ counts, int* __restrict__ flag) {
  const int bid = blockIdx.x, t = threadIdx.x;
  if (bid < 79) {
    int i = bid * 256 + t;
    if (i < NN) counts[i] = 0;
    return;
  }
  __shared__ int cs[256], ct[256];
  int sane = 0, tot = 0;
  for (int i = 2 * t; i < 16384; i += 512) {
    unsigned short v = x[i];
    int e = (v >> 7) & 0xFF;
    tot++;
    if (v == 0 || (e >= 80 && e <= 170)) sane++;
  }
  cs[t] = sane; ct[t] = tot;
  __syncthreads();
  for (int o = 128; o > 0; o >>= 1) {
    if (t < o) { cs[t] += cs[t + o]; ct[t] += ct[t + o]; }
    __syncthreads();
  }
  if (t == 0) *flag = (cs[0] * 10 > ct[0] * 7) ? 1 : 0;
}

// ---------------------------------------------------------------------------
// convert_all: one grid-stride kernel for every input canonicalization.
// ---------------------------------------------------------------------------
#define CX  (NN * DD)
#define CE  (NE * DD)
#define CW0 (NITER * 384 * DD)
#define CW1 (NITER * 128 * DD)
#define CNW0 (NITER * 256 * DD)
#define CB  (NITER * DD)
#define BX0 CX
#define BX1 (BX0 + CE)
#define BX7 (BX1 + CW0 + CW1 + CW1 + CNW0 + CW1 + CW1)
#define BX8 (BX7 + 10 * CB)

struct CvtP {
  const void *x, *e;
  const void* w[6];
  bf16 *xb, *eb;
  bf16* wt[6];
  const void* bs[10];
  float* bd[10];
  const int* flag;
};

__global__ void convert_all(CvtP P) {
  const int fl = *P.flag;
  const int gstride = gridDim.x * 256;
  for (int i = blockIdx.x * 256 + threadIdx.x; i < BX8; i += gstride) {
    if (i < BX0) {
      P.xb[i] = (bf16)readin(P.x, i, fl);
    } else if (i < BX1) {
      P.eb[i - BX0] = (bf16)readin(P.e, i - BX0, fl);
    } else if (i < BX7) {
      int j = i - BX1, w;
      if (j < CW0) { w = 0; }
      else if ((j -= CW0) < CW1) { w = 1; }
      else if ((j -= CW1) < CW1) { w = 2; }
      else if ((j -= CW1) < CNW0) { w = 3; }
      else if ((j -= CNW0) < CW1) { w = 4; }
      else { j -= CW1; w = 5; }
      const int K = (w == 0) ? 384 : (w == 3) ? 256 : 128;
      float v = readin(P.w[w], j, fl);
      int it = j / (K * DD);
      int rem = j - it * K * DD;
      int k = rem >> 7, n = rem & 127;
      P.wt[w][(size_t)it * K * DD + (size_t)n * K + k] = (bf16)v;
    } else {
      int j = i - BX7;
      int b = j / CB, r = j - b * CB;
      P.bd[b][r] = readin(P.bs[b], r, fl);
    }
  }
}

// ---------------------------------------------------------------------------
// Fused 3-layer MLP, NW waves (16 rows each), 128-col tile.
// B staged double-buffered via global_load_lds; A direct-to-register 1-deep
// prefetch; LDS-free LayerNorm; bf16 residual RMW.
//
// ROUND-5 CHANGE (T4, guide m218): __syncthreads() (which drains vmcnt(0),
// killing the DMA prefetch overlap — the m97 stall) is replaced per slab by:
//   issue DMA(s+1) ; s_waitcnt vmcnt(N) ; s_barrier ; [sched_barrier]
//   compute slab s ; [sched_barrier] ; s_barrier
// N counts exactly the vmem ops issued after DMA(s), so DMA(s+1)/gatherA(s+1)
// stay in flight ACROSS the barrier and their latency hides under compute.
// First barrier: everyone's DMA(s) landed (own-wave via vmcnt, cross-wave via
// barrier). Second barrier: nobody still reads buf s&1 when it's re-DMA'd.
// sched_barrier(0) pins keep the compiler from hoisting/sinking the Bls
// ds_reads across the barriers (guide rules #18/m152).
//
// Round 1-2 lesson: direct-B-from-global 2-3x worse than staging. Round-3
// lesson: aggregate stays a separate fat-grid kernel.
//
// AMODE 1: A0 = concat(xb[row[m]], xb[col[m]], eb[m])  (K0=384)
// AMODE 2: A0 = concat(xb[m], aggb[m])                 (K0=256)
// ---------------------------------------------------------------------------
template<int K0, int AMODE, int NW>
__global__ __launch_bounds__(NW * 64, NW == 8 ? 6 : 4) void fused_mlp(
    const bf16* S0b,                 // xb (may alias st for AMODE 2)
    const bf16* S1b,                 // eb (AMODE 1, aliases st) / aggb (AMODE 2)
    const int*  __restrict__ eidx,
    const bf16* __restrict__ W0t, const bf16* __restrict__ W1t,
    const bf16* __restrict__ W2t,
    const float* __restrict__ b0, const float* __restrict__ b1,
    const float* __restrict__ b2,
    const float* __restrict__ gamma, const float* __restrict__ beta,
    bf16* st, int M)
{
  constexpr int NS1  = K0 / 32;      // 12 or 8 (even)
  constexpr int ROWS = NW * 16;
  constexpr int DN   = (NW == 8) ? 1 : 2;   // gload16 instrs per dmaW
  __shared__ __align__(16) bf16 Bls[2][128 * 32];
  __shared__ __align__(16) bf16 Hls[ROWS * HSTRIDE];

  const int tid  = threadIdx.x;
  const int lane = tid & 63;
  const int wv   = tid >> 6;
  const int l15  = lane & 15, quad = lane >> 4;
  const int m0   = blockIdx.x * ROWS;
  const int scol = tid >> 2;
  const int sk8  = (tid & 3) * 8;

  const int rowm = min(m0 + wv * 16 + l15, M - 1);
  int ir = 0, ic = 0;
  if (AMODE == 1) { ir = eidx[rowm]; ic = eidx[NE + rowm]; }

  auto dmaW = [&](const bf16* W, int K, int kk, int buf) {
    gload16(W + (size_t)scol * K + kk + sk8, &Bls[buf][scol * 32 + sk8]);
    if (NW == 4)
      gload16(W + (size_t)(scol + 64) * K + kk + sk8, &Bls[buf][(scol + 64) * 32 + sk8]);
  };
  auto gatherA = [&](int kk, short8* a) {
    const int ks = (kk & 127) + quad * 8;
    const bf16* base;
    if (AMODE == 1) {
      const int seg = kk >> 7;
      base = (seg == 0) ? S0b + (size_t)ir * DD
           : (seg == 1) ? S0b + (size_t)ic * DD
                        : S1b + (size_t)rowm * DD;
    } else {
      base = (kk >> 7) ? S1b + (size_t)rowm * DD
                       : S0b + (size_t)rowm * DD;
    }
    *a = *(const short8*)(base + ks);
  };

  f32x4 acc[8];
  auto zacc = [&]() {
#pragma unroll
    for (int j = 0; j < 8; j++) acc[j] = (f32x4){0.f, 0.f, 0.f, 0.f};
  };
  auto slabMfmaA = [&](short8 a, int buf) {
    short8 bfr[8];
#pragma unroll
    for (int ni = 0; ni < 8; ni++)
      bfr[ni] = *(const short8*)&Bls[buf][(ni * 16 + l15) * 32 + quad * 8];
#pragma unroll
    for (int ni = 0; ni < 8; ni++)
      acc[ni] = __builtin_amdgcn_mfma_f32_16x16x32_bf16(a, bfr[ni], acc[ni], 0, 0, 0);
  };
  auto slabMfmaH = [&](int kk, int buf) {
    short8 a = *(const short8*)&Hls[(wv * 16 + l15) * HSTRIDE + kk + quad * 8];
    short8 bfr[8];
#pragma unroll
    for (int ni = 0; ni < 8; ni++)
      bfr[ni] = *(const short8*)&Bls[buf][(ni * 16 + l15) * 32 + quad * 8];
#pragma unroll
    for (int ni = 0; ni < 8; ni++)
      acc[ni] = __builtin_amdgcn_mfma_f32_16x16x32_bf16(a, bfr[ni], acc[ni], 0, 0, 0);
  };
  auto writeH = [&](const float* bias) {
    float bv[8];
#pragma unroll
    for (int ni = 0; ni < 8; ni++) bv[ni] = bias[ni * 16 + l15];
#pragma unroll
    for (int r = 0; r < 4; r++) {
      const int row = wv * 16 + quad * 4 + r;
#pragma unroll
      for (int ni = 0; ni < 8; ni++)
        Hls[row * HSTRIDE + ni * 16 + l15] = (bf16)fmaxf(acc[ni][r] + bv[ni], 0.f);
    }
  };

  // Phase 1
  zacc();
  short8 aCur, aNxt;
  dmaW(W0t, K0, 0, 0);
  gatherA(0, &aCur);
#pragma unroll
  for (int s = 0; s < NS1; s++) {
    int cnt;
    if (s + 1 < NS1) {
      dmaW(W0t, K0, (s + 1) * 32, (s + 1) & 1);
      gatherA((s + 1) * 32, &aNxt);
      cnt = 1 + DN + 1;              // gatherA(s) + DMA(s+1) + gatherA(s+1)
    } else {
      dmaW(W1t, 128, 0, NS1 & 1);
      cnt = 1 + DN;                  // gatherA(s) + DMA(next)
    }
    waitVm(cnt);
    __builtin_amdgcn_s_barrier();
    __builtin_amdgcn_sched_barrier(0);
    slabMfmaA(aCur, s & 1);
    __builtin_amdgcn_sched_barrier(0);
    __builtin_amdgcn_s_barrier();
    aCur = aNxt;
  }
  writeH(b0);

  // Phase 2
  zacc();
#pragma unroll
  for (int s = 0; s < 4; s++) {
    if (s < 3) dmaW(W1t, 128, (s + 1) * 32, (NS1 + s + 1) & 1);
    else       dmaW(W2t, 128, 0,            (NS1 + 4) & 1);
    waitVm(DN);                      // allow this iter's DMA in flight
    __builtin_amdgcn_s_barrier();
    __builtin_amdgcn_sched_barrier(0);
    slabMfmaH(s * 32, (NS1 + s) & 1);
    __builtin_amdgcn_sched_barrier(0);
    __builtin_amdgcn_s_barrier();
  }
  writeH(b1);

  // Phase 3 + LN + residual
  zacc();
#pragma unroll
  for (int s = 0; s < 4; s++) {
    int cnt = 0;
    if (s < 3) { dmaW(W2t, 128, (s + 1) * 32, (NS1 + 4 + s + 1) & 1); cnt = DN; }
    waitVm(cnt);
    __builtin_amdgcn_s_barrier();
    __builtin_amdgcn_sched_barrier(0);
    slabMfmaH(s * 32, (NS1 + 4 + s) & 1);
    if (s < 3) {
      __builtin_amdgcn_sched_barrier(0);
      __builtin_amdgcn_s_barrier();
    }
  }

  float bv[8], gv[8], btv[8];
#pragma unroll
  for (int ni = 0; ni < 8; ni++) {
    const int col = ni * 16 + l15;
    bv[ni] = b2[col]; gv[ni] = gamma[col]; btv[ni] = beta[col];
  }
#pragma unroll
  for (int r = 0; r < 4; r++) {
    float a = 0.f, bq = 0.f;
#pragma unroll
    for (int ni = 0; ni < 8; ni++) {
      const float v = acc[ni][r] + bv[ni];
      a += v; bq += v * v;
    }
#pragma unroll
    for (int off = 1; off < 16; off <<= 1) {
      a  += __shfl_xor(a, off);
      bq += __shfl_xor(bq, off);
    }
    const float mu = a * (1.0f / 128.0f);
    const float var = fmaxf(bq * (1.0f / 128.0f) - mu * mu, 0.0f);
    const float rs = rsqrtf(var + 1e-5f);
    const int m = m0 + wv * 16 + quad * 4 + r;
    if (m < M) {
#pragma unroll
      for (int ni = 0; ni < 8; ni++) {
        const int col = ni * 16 + l15;
        const float v = acc[ni][r] + bv[ni];
        const float lnv = (v - mu) * rs * gv[ni] + btv[ni];
        const size_t idx = (size_t)m * DD + col;
        st[idx] = (bf16)(lnv + (float)st[idx]);
      }
    }
  }
}

// --------------------------- CSR build + aggregate -------------------------
__global__ void hist_kernel(const int* __restrict__ eidx, int* __restrict__ counts) {
  int e = blockIdx.x * 256 + threadIdx.x;
  if (e < NE) atomicAdd(&counts[eidx[NE + e]], 1);
}

__global__ void scan_kernel(const int* __restrict__ counts, int* __restrict__ offs,
                            int* __restrict__ cursor) {
  __shared__ int sums[1024];
  const int t = threadIdx.x;
  const int base = t * 20;
  int local[20];
  int s = 0;
  for (int i = 0; i < 20; i++) {
    int idx = base + i;
    int c = (idx < NN) ? counts[idx] : 0;
    local[i] = s; s += c;
  }
  sums[t] = s;
  __syncthreads();
  for (int off = 1; off < 1024; off <<= 1) {
    int v = 0;
    if (t >= off) v = sums[t - off];
    __syncthreads();
    if (t >= off) sums[t] += v;
    __syncthreads();
  }
  int excl = (t == 0) ? 0 : sums[t - 1];
  for (int i = 0; i < 20; i++) {
    int idx = base + i;
    if (idx < NN) { offs[idx] = excl + local[i]; cursor[idx] = 0; }
  }
  if (t == 1023) offs[NN] = sums[1023];
}

__global__ void fill_kernel(const int* __restrict__ eidx, const int* __restrict__ offs,
                            int* __restrict__ cursor, int* __restrict__ sorted) {
  int e = blockIdx.x * 256 + threadIdx.x;
  if (e < NE) {
    int n = eidx[NE + e];
    int p = atomicAdd(&cursor[n], 1);
    sorted[offs[n] + p] = e;
  }
}

// wave per node (fat grid: 20000 waves, 32 waves/CU -> latency well hidden):
// packed-uint bf16x2 loads, fp32 sums, bf16 out.
__global__ void aggregate_kernel(const bf16* __restrict__ eb, const int* __restrict__ offs,
                                 const int* __restrict__ sorted, bf16* __restrict__ aggb) {
  const int node = blockIdx.x * 4 + (threadIdx.x >> 6);
  const int lane = threadIdx.x & 63;
  if (node >= NN) return;
  const int s = offs[node], t = offs[node + 1];
  float a0 = 0.f, a1 = 0.f;
  for (int i = s; i < t; i++) {
    const int e = sorted[i];
    unsigned int v = *(const unsigned int*)(eb + (size_t)e * DD + 2 * lane);
    a0 += bfbits2f(v << 16);
    a1 += bfbits2f(v & 0xFFFF0000u);
  }
  bf16 o0 = (bf16)a0, o1 = (bf16)a1;
  unsigned int pack = (unsigned int)(*(unsigned short*)&o0)
                    | ((unsigned int)(*(unsigned short*)&o1) << 16);
  *(unsigned int*)(aggb + (size_t)node * DD + 2 * lane) = pack;
}

// bf16 states -> d_out in detected dtype
__global__ void outwb_kernel(const bf16* __restrict__ xb, const bf16* __restrict__ eb,
                             void* __restrict__ out, const int* __restrict__ flag) {
  int i = blockIdx.x * 256 + threadIdx.x;
  const int nx = NN * DD, total = (NN + NE) * DD;
  if (i < total) {
    bf16 v = (i < nx) ? xb[i] : eb[i - nx];
    if (*flag) ((bf16*)out)[i] = v;
    else       ((float*)out)[i] = (float)v;
  }
}

// ---------------------------------------------------------------------------
extern "C" void kernel_launch(void* const* d_in, const int* in_sizes, int n_in,
                              void* d_out, int out_size, void* d_ws, size_t ws_size,
                              hipStream_t stream) {
  const int* eidx = (const int*)d_in[18];

  char* ws = (char*)d_ws;
  size_t off = 0;
  auto alloc = [&](size_t bytes) -> char* {
    char* p = ws + off;
    off = (off + bytes + 255) & ~(size_t)255;
    return p;
  };

  bf16* xb   = (bf16*)alloc((size_t)NN * DD * 2);
  bf16* eb   = (bf16*)alloc((size_t)NE * DD * 2);
  bf16* aggb = (bf16*)alloc((size_t)NN * DD * 2);
  bf16* eW0t = (bf16*)alloc((size_t)CW0 * 2);
  bf16* eW1t = (bf16*)alloc((size_t)CW1 * 2);
  bf16* eW2t = (bf16*)alloc((size_t)CW1 * 2);
  bf16* nW0t = (bf16*)alloc((size_t)CNW0 * 2);
  bf16* nW1t = (bf16*)alloc((size_t)CW1 * 2);
  bf16* nW2t = (bf16*)alloc((size_t)CW1 * 2);
  float* bf_[10];
  for (int i = 0; i < 10; i++) bf_[i] = (float*)alloc(CB * 4);
  int* counts = (int*)alloc((size_t)NN * 4);
  int* cursor = (int*)alloc((size_t)NN * 4);
  int* offs   = (int*)alloc((size_t)(NN + 1) * 4);
  int* sorted = (int*)alloc((size_t)NE * 4);
  int* flag   = (int*)alloc(4);

  // 1) zero counts + detect dtype
  detzero_kernel<<<80, 256, 0, stream>>>((const unsigned short*)d_in[0], counts, flag);

  // 2) all conversions in one kernel
  CvtP C;
  C.x = d_in[0]; C.e = d_in[1];
  C.w[0] = d_in[2];  C.w[1] = d_in[4];  C.w[2] = d_in[6];
  C.w[3] = d_in[10]; C.w[4] = d_in[12]; C.w[5] = d_in[14];
  C.xb = xb; C.eb = eb;
  C.wt[0] = eW0t; C.wt[1] = eW1t; C.wt[2] = eW2t;
  C.wt[3] = nW0t; C.wt[4] = nW1t; C.wt[5] = nW2t;
  const int bsrc_idx[10] = {3, 5, 7, 8, 9, 11, 13, 15, 16, 17};
  for (int i = 0; i < 10; i++) { C.bs[i] = d_in[bsrc_idx[i]]; C.bd[i] = bf_[i]; }
  C.flag = flag;
  convert_all<<<2048, 256, 0, stream>>>(C);

  // 3) CSR
  hist_kernel<<<(NE + 255) / 256, 256, 0, stream>>>(eidx, counts);
  scan_kernel<<<1, 1024, 0, stream>>>(counts, offs, cursor);
  fill_kernel<<<(NE + 255) / 256, 256, 0, stream>>>(eidx, offs, cursor, sorted);

  const int egrid = NE / 128;               // 625 (8-wave, 128-row blocks)
  const int ngrid = (NN + 63) / 64;         // 313 (4-wave, 64-row blocks)

  // 4) message passing: 3 dispatches per iteration
  for (int t = 0; t < NITER; t++) {
    fused_mlp<384, 1, 8><<<egrid, 512, 0, stream>>>(
        xb, eb, eidx,
        eW0t + (size_t)t * 384 * DD, eW1t + (size_t)t * 128 * DD,
        eW2t + (size_t)t * 128 * DD,
        bf_[0] + t * DD, bf_[1] + t * DD, bf_[2] + t * DD,
        bf_[3] + t * DD, bf_[4] + t * DD, eb, NE);
    aggregate_kernel<<<(NN + 3) / 4, 256, 0, stream>>>(eb, offs, sorted, aggb);
    fused_mlp<256, 2, 4><<<ngrid, 256, 0, stream>>>(
        xb, aggb, nullptr,
        nW0t + (size_t)t * 256 * DD, nW1t + (size_t)t * 128 * DD,
        nW2t + (size_t)t * 128 * DD,
        bf_[5] + t * DD, bf_[6] + t * DD, bf_[7] + t * DD,
        bf_[8] + t * DD, bf_[9] + t * DD, xb, NN);
  }

  // 5) output
  outwb_kernel<<<((NN + NE) * DD + 255) / 256, 256, 0, stream>>>(xb, eb, d_out, flag);
}

// Round 6
// 1079.460 us; speedup vs baseline: 2.7433x; 1.0171x over previous
//
#include <hip/hip_runtime.h>
#include <hip/hip_bf16.h>

typedef __hip_bfloat16 bf16;
typedef __attribute__((ext_vector_type(8))) short short8;
typedef __attribute__((ext_vector_type(4))) float f32x4;

#define NN 20000
#define NE 80000
#define DD 128
#define NITER 15
#define HSTRIDE 136   // 272 B row stride: 16B-aligned rows, 2-way LDS aliasing (free)

__device__ inline void gload16(const void* g, void* l) {
  __builtin_amdgcn_global_load_lds(
      (const __attribute__((address_space(1))) void*)g,
      (__attribute__((address_space(3))) void*)l, 16, 0, 0);
}

// counted vmem wait: allow exactly n newest vector-memory ops to stay in
// flight; everything older (the slab we're about to consume) must land.
__device__ inline void waitVm(int n) {
  switch (n) {
    case 0: asm volatile("s_waitcnt vmcnt(0)" ::: "memory"); break;
    case 1: asm volatile("s_waitcnt vmcnt(1)" ::: "memory"); break;
    case 2: asm volatile("s_waitcnt vmcnt(2)" ::: "memory"); break;
    case 3: asm volatile("s_waitcnt vmcnt(3)" ::: "memory"); break;
    case 4: asm volatile("s_waitcnt vmcnt(4)" ::: "memory"); break;
    case 5: asm volatile("s_waitcnt vmcnt(5)" ::: "memory"); break;
    default: asm volatile("s_waitcnt vmcnt(6)" ::: "memory"); break;
  }
}

__device__ inline float bfbits2f(unsigned int hi16) {
  union { unsigned int u; float f; } c; c.u = hi16; return c.f;
}

__device__ inline float readin(const void* p, int i, int fl) {
  return fl ? (float)((const bf16*)p)[i] : ((const float*)p)[i];
}

// ---------------------------------------------------------------------------
// detzero: blocks 0..78 zero counts; block 79 runs dtype detection.
// flag = 1 -> bf16 inputs ; flag = 0 -> fp32 inputs.
// ---------------------------------------------------------------------------
__global__ void detzero_kernel(const unsigned short* __restrict__ x,
                               int* __restrict__ counts, int* __restrict__ flag) {
  const int bid = blockIdx.x, t = threadIdx.x;
  if (bid < 79) {
    int i = bid * 256 + t;
    if (i < NN) counts[i] = 0;
    return;
  }
  __shared__ int cs[256], ct[256];
  int sane = 0, tot = 0;
  for (int i = 2 * t; i < 16384; i += 512) {
    unsigned short v = x[i];
    int e = (v >> 7) & 0xFF;
    tot++;
    if (v == 0 || (e >= 80 && e <= 170)) sane++;
  }
  cs[t] = sane; ct[t] = tot;
  __syncthreads();
  for (int o = 128; o > 0; o >>= 1) {
    if (t < o) { cs[t] += cs[t + o]; ct[t] += ct[t + o]; }
    __syncthreads();
  }
  if (t == 0) *flag = (cs[0] * 10 > ct[0] * 7) ? 1 : 0;
}

// ---------------------------------------------------------------------------
// convert_all: one grid-stride kernel for every input canonicalization.
// Weight transpose now ALSO bakes in the B-tile bank-deconflict swizzle:
// logical k-octet q = (k>>3)&3 is stored at physical q ^ ((n>>1)&3), so the
// linear global_load_lds staging + swizzled ds_read in fused_mlp form a
// matched involution (guide rule #21).
// ---------------------------------------------------------------------------
#define CX  (NN * DD)
#define CE  (NE * DD)
#define CW0 (NITER * 384 * DD)
#define CW1 (NITER * 128 * DD)
#define CNW0 (NITER * 256 * DD)
#define CB  (NITER * DD)
#define BX0 CX
#define BX1 (BX0 + CE)
#define BX7 (BX1 + CW0 + CW1 + CW1 + CNW0 + CW1 + CW1)
#define BX8 (BX7 + 10 * CB)

struct CvtP {
  const void *x, *e;
  const void* w[6];
  bf16 *xb, *eb;
  bf16* wt[6];
  const void* bs[10];
  float* bd[10];
  const int* flag;
};

__global__ void convert_all(CvtP P) {
  const int fl = *P.flag;
  const int gstride = gridDim.x * 256;
  for (int i = blockIdx.x * 256 + threadIdx.x; i < BX8; i += gstride) {
    if (i < BX0) {
      P.xb[i] = (bf16)readin(P.x, i, fl);
    } else if (i < BX1) {
      P.eb[i - BX0] = (bf16)readin(P.e, i - BX0, fl);
    } else if (i < BX7) {
      int j = i - BX1, w;
      if (j < CW0) { w = 0; }
      else if ((j -= CW0) < CW1) { w = 1; }
      else if ((j -= CW1) < CW1) { w = 2; }
      else if ((j -= CW1) < CNW0) { w = 3; }
      else if ((j -= CNW0) < CW1) { w = 4; }
      else { j -= CW1; w = 5; }
      const int K = (w == 0) ? 384 : (w == 3) ? 256 : 128;
      float v = readin(P.w[w], j, fl);
      int it = j / (K * DD);
      int rem = j - it * K * DD;
      int k = rem >> 7, n = rem & 127;
      // bank-deconflict swizzle: permute 8-elem octets within each 32-K slab
      int q  = (k >> 3) & 3;
      int kp = (k & ~24) | (((q ^ ((n >> 1) & 3)) & 3) << 3);
      P.wt[w][(size_t)it * K * DD + (size_t)n * K + kp] = (bf16)v;
    } else {
      int j = i - BX7;
      int b = j / CB, r = j - b * CB;
      P.bd[b][r] = readin(P.bs[b], r, fl);
    }
  }
}

// ---------------------------------------------------------------------------
// Fused 3-layer MLP, NW waves x MI row-groups (16 rows each), 128-col tile.
// B staged double-buffered via global_load_lds; counted-vmcnt T4 barriers
// (round-5, measured win); A direct-to-register 1-deep prefetch; LDS-free
// LayerNorm; bf16 residual RMW.
//
// ROUND-6 CHANGES:
//  * MI=2 on edge: each B-fragment ds_read feeds 2 MFMA -> per-CU B-read
//    LDS traffic halves (was the critical path: 8KB/wave/slab for 8 MFMA).
//    Staging kept (rounds 1-2: direct-B 2-3x worse). 128-row blocks,
//    grid stays 625, LDS 50.8KB -> 3 blocks/CU (12 waves).
//  * B-read bank swizzle (matched to convert_all): read octet
//    quad ^ ((row>>1)&3) -> quarter-wave phases spread across all four
//    4-bank groups (8-way phase conflict -> 2-way = free, m136).
//
// AMODE 1: A0 = concat(xb[row[m]], xb[col[m]], eb[m])  (K0=384)
// AMODE 2: A0 = concat(xb[m], aggb[m])                 (K0=256)
// ---------------------------------------------------------------------------
template<int K0, int AMODE, int NW, int MI>
__global__ __launch_bounds__(NW * 64, MI == 2 ? 3 : 4) void fused_mlp(
    const bf16* S0b,                 // xb (may alias st for AMODE 2)
    const bf16* S1b,                 // eb (AMODE 1, aliases st) / aggb (AMODE 2)
    const int*  __restrict__ eidx,
    const bf16* __restrict__ W0t, const bf16* __restrict__ W1t,
    const bf16* __restrict__ W2t,
    const float* __restrict__ b0, const float* __restrict__ b1,
    const float* __restrict__ b2,
    const float* __restrict__ gamma, const float* __restrict__ beta,
    bf16* st, int M)
{
  constexpr int NS1  = K0 / 32;      // 12 or 8 (even)
  constexpr int RPW  = 16 * MI;      // rows per wave
  constexpr int ROWS = NW * RPW;
  constexpr int DN   = 2;            // gload16 instrs per dmaW (256 threads)
  __shared__ __align__(16) bf16 Bls[2][128 * 32];
  __shared__ __align__(16) bf16 Hls[ROWS * HSTRIDE];

  const int tid  = threadIdx.x;
  const int lane = tid & 63;
  const int wv   = tid >> 6;
  const int l15  = lane & 15, quad = lane >> 4;
  const int m0   = blockIdx.x * ROWS;
  const int scol = tid >> 2;
  const int sk8  = (tid & 3) * 8;

  int rowm[MI], ir[MI], ic[MI];
#pragma unroll
  for (int g = 0; g < MI; g++) {
    rowm[g] = min(m0 + wv * RPW + g * 16 + l15, M - 1);
    ir[g] = 0; ic[g] = 0;
    if (AMODE == 1) { ir[g] = eidx[rowm[g]]; ic[g] = eidx[NE + rowm[g]]; }
  }

  auto dmaW = [&](const bf16* W, int K, int kk, int buf) {
    gload16(W + (size_t)scol * K + kk + sk8,        &Bls[buf][scol * 32 + sk8]);
    gload16(W + (size_t)(scol + 64) * K + kk + sk8, &Bls[buf][(scol + 64) * 32 + sk8]);
  };
  auto gatherA = [&](int g, int kk, short8* a) {
    const int ks = (kk & 127) + quad * 8;
    const bf16* base;
    if (AMODE == 1) {
      const int seg = kk >> 7;
      base = (seg == 0) ? S0b + (size_t)ir[g] * DD
           : (seg == 1) ? S0b + (size_t)ic[g] * DD
                        : S1b + (size_t)rowm[g] * DD;
    } else {
      base = (kk >> 7) ? S1b + (size_t)rowm[g] * DD
                       : S0b + (size_t)rowm[g] * DD;
    }
    *a = *(const short8*)(base + ks);
  };

  // swizzled B-fragment read (matches convert_all's octet permutation)
  auto readB = [&](int buf, short8* bfr) {
#pragma unroll
    for (int ni = 0; ni < 8; ni++) {
      const int r = ni * 16 + l15;
      bfr[ni] = *(const short8*)&Bls[buf][r * 32 + ((quad ^ ((r >> 1) & 3)) & 3) * 8];
    }
  };

  f32x4 acc[MI][8];
  auto zacc = [&]() {
#pragma unroll
    for (int g = 0; g < MI; g++)
#pragma unroll
      for (int j = 0; j < 8; j++) acc[g][j] = (f32x4){0.f, 0.f, 0.f, 0.f};
  };
  auto slabMfmaA = [&](short8* a, int buf) {
    short8 bfr[8];
    readB(buf, bfr);
#pragma unroll
    for (int g = 0; g < MI; g++)
#pragma unroll
      for (int ni = 0; ni < 8; ni++)
        acc[g][ni] = __builtin_amdgcn_mfma_f32_16x16x32_bf16(a[g], bfr[ni], acc[g][ni], 0, 0, 0);
  };
  auto slabMfmaH = [&](int kk, int buf) {
    short8 bfr[8];
    readB(buf, bfr);
#pragma unroll
    for (int g = 0; g < MI; g++) {
      short8 a = *(const short8*)&Hls[(wv * RPW + g * 16 + l15) * HSTRIDE + kk + quad * 8];
#pragma unroll
      for (int ni = 0; ni < 8; ni++)
        acc[g][ni] = __builtin_amdgcn_mfma_f32_16x16x32_bf16(a, bfr[ni], acc[g][ni], 0, 0, 0);
    }
  };
  auto writeH = [&](const float* bias) {
    float bv[8];
#pragma unroll
    for (int ni = 0; ni < 8; ni++) bv[ni] = bias[ni * 16 + l15];
#pragma unroll
    for (int g = 0; g < MI; g++)
#pragma unroll
      for (int r = 0; r < 4; r++) {
        const int row = wv * RPW + g * 16 + quad * 4 + r;
#pragma unroll
        for (int ni = 0; ni < 8; ni++)
          Hls[row * HSTRIDE + ni * 16 + l15] = (bf16)fmaxf(acc[g][ni][r] + bv[ni], 0.f);
      }
  };

  // Phase 1
  zacc();
  short8 aCur[MI], aNxt[MI];
  dmaW(W0t, K0, 0, 0);
#pragma unroll
  for (int g = 0; g < MI; g++) gatherA(g, 0, &aCur[g]);
#pragma unroll
  for (int s = 0; s < NS1; s++) {
    int cnt;
    if (s + 1 < NS1) {
      dmaW(W0t, K0, (s + 1) * 32, (s + 1) & 1);
#pragma unroll
      for (int g = 0; g < MI; g++) gatherA(g, (s + 1) * 32, &aNxt[g]);
      cnt = MI + DN + MI;            // gatherA(s) + DMA(s+1) + gatherA(s+1)
    } else {
      dmaW(W1t, 128, 0, NS1 & 1);
      cnt = MI + DN;                 // gatherA(s) + DMA(next)
    }
    waitVm(cnt);
    __builtin_amdgcn_s_barrier();
    __builtin_amdgcn_sched_barrier(0);
    slabMfmaA(aCur, s & 1);
    __builtin_amdgcn_sched_barrier(0);
    __builtin_amdgcn_s_barrier();
#pragma unroll
    for (int g = 0; g < MI; g++) aCur[g] = aNxt[g];
  }
  writeH(b0);

  // Phase 2
  zacc();
#pragma unroll
  for (int s = 0; s < 4; s++) {
    if (s < 3) dmaW(W1t, 128, (s + 1) * 32, (NS1 + s + 1) & 1);
    else       dmaW(W2t, 128, 0,            (NS1 + 4) & 1);
    waitVm(DN);                      // allow this iter's DMA in flight
    __builtin_amdgcn_s_barrier();
    __builtin_amdgcn_sched_barrier(0);
    slabMfmaH(s * 32, (NS1 + s) & 1);
    __builtin_amdgcn_sched_barrier(0);
    __builtin_amdgcn_s_barrier();
  }
  writeH(b1);

  // Phase 3 + LN + residual
  zacc();
#pragma unroll
  for (int s = 0; s < 4; s++) {
    int cnt = 0;
    if (s < 3) { dmaW(W2t, 128, (s + 1) * 32, (NS1 + 4 + s + 1) & 1); cnt = DN; }
    waitVm(cnt);
    __builtin_amdgcn_s_barrier();
    __builtin_amdgcn_sched_barrier(0);
    slabMfmaH(s * 32, (NS1 + 4 + s) & 1);
    if (s < 3) {
      __builtin_amdgcn_sched_barrier(0);
      __builtin_amdgcn_s_barrier();
    }
  }

  float bv[8], gv[8], btv[8];
#pragma unroll
  for (int ni = 0; ni < 8; ni++) {
    const int col = ni * 16 + l15;
    bv[ni] = b2[col]; gv[ni] = gamma[col]; btv[ni] = beta[col];
  }
#pragma unroll
  for (int g = 0; g < MI; g++) {
#pragma unroll
    for (int r = 0; r < 4; r++) {
      float a = 0.f, bq = 0.f;
#pragma unroll
      for (int ni = 0; ni < 8; ni++) {
        const float v = acc[g][ni][r] + bv[ni];
        a += v; bq += v * v;
      }
#pragma unroll
      for (int off = 1; off < 16; off <<= 1) {
        a  += __shfl_xor(a, off);
        bq += __shfl_xor(bq, off);
      }
      const float mu = a * (1.0f / 128.0f);
      const float var = fmaxf(bq * (1.0f / 128.0f) - mu * mu, 0.0f);
      const float rs = rsqrtf(var + 1e-5f);
      const int m = m0 + wv * RPW + g * 16 + quad * 4 + r;
      if (m < M) {
#pragma unroll
        for (int ni = 0; ni < 8; ni++) {
          const int col = ni * 16 + l15;
          const float v = acc[g][ni][r] + bv[ni];
          const float lnv = (v - mu) * rs * gv[ni] + btv[ni];
          const size_t idx = (size_t)m * DD + col;
          st[idx] = (bf16)(lnv + (float)st[idx]);
        }
      }
    }
  }
}

// --------------------------- CSR build + aggregate -------------------------
__global__ void hist_kernel(const int* __restrict__ eidx, int* __restrict__ counts) {
  int e = blockIdx.x * 256 + threadIdx.x;
  if (e < NE) atomicAdd(&counts[eidx[NE + e]], 1);
}

__global__ void scan_kernel(const int* __restrict__ counts, int* __restrict__ offs,
                            int* __restrict__ cursor) {
  __shared__ int sums[1024];
  const int t = threadIdx.x;
  const int base = t * 20;
  int local[20];
  int s = 0;
  for (int i = 0; i < 20; i++) {
    int idx = base + i;
    int c = (idx < NN) ? counts[idx] : 0;
    local[i] = s; s += c;
  }
  sums[t] = s;
  __syncthreads();
  for (int off = 1; off < 1024; off <<= 1) {
    int v = 0;
    if (t >= off) v = sums[t - off];
    __syncthreads();
    if (t >= off) sums[t] += v;
    __syncthreads();
  }
  int excl = (t == 0) ? 0 : sums[t - 1];
  for (int i = 0; i < 20; i++) {
    int idx = base + i;
    if (idx < NN) { offs[idx] = excl + local[i]; cursor[idx] = 0; }
  }
  if (t == 1023) offs[NN] = sums[1023];
}

__global__ void fill_kernel(const int* __restrict__ eidx, const int* __restrict__ offs,
                            int* __restrict__ cursor, int* __restrict__ sorted) {
  int e = blockIdx.x * 256 + threadIdx.x;
  if (e < NE) {
    int n = eidx[NE + e];
    int p = atomicAdd(&cursor[n], 1);
    sorted[offs[n] + p] = e;
  }
}

// wave per node (fat grid: 20000 waves, 32 waves/CU -> latency well hidden):
// packed-uint bf16x2 loads, fp32 sums, bf16 out.
__global__ void aggregate_kernel(const bf16* __restrict__ eb, const int* __restrict__ offs,
                                 const int* __restrict__ sorted, bf16* __restrict__ aggb) {
  const int node = blockIdx.x * 4 + (threadIdx.x >> 6);
  const int lane = threadIdx.x & 63;
  if (node >= NN) return;
  const int s = offs[node], t = offs[node + 1];
  float a0 = 0.f, a1 = 0.f;
  for (int i = s; i < t; i++) {
    const int e = sorted[i];
    unsigned int v = *(const unsigned int*)(eb + (size_t)e * DD + 2 * lane);
    a0 += bfbits2f(v << 16);
    a1 += bfbits2f(v & 0xFFFF0000u);
  }
  bf16 o0 = (bf16)a0, o1 = (bf16)a1;
  unsigned int pack = (unsigned int)(*(unsigned short*)&o0)
                    | ((unsigned int)(*(unsigned short*)&o1) << 16);
  *(unsigned int*)(aggb + (size_t)node * DD + 2 * lane) = pack;
}

// bf16 states -> d_out in detected dtype
__global__ void outwb_kernel(const bf16* __restrict__ xb, const bf16* __restrict__ eb,
                             void* __restrict__ out, const int* __restrict__ flag) {
  int i = blockIdx.x * 256 + threadIdx.x;
  const int nx = NN * DD, total = (NN + NE) * DD;
  if (i < total) {
    bf16 v = (i < nx) ? xb[i] : eb[i - nx];
    if (*flag) ((bf16*)out)[i] = v;
    else       ((float*)out)[i] = (float)v;
  }
}

// ---------------------------------------------------------------------------
extern "C" void kernel_launch(void* const* d_in, const int* in_sizes, int n_in,
                              void* d_out, int out_size, void* d_ws, size_t ws_size,
                              hipStream_t stream) {
  const int* eidx = (const int*)d_in[18];

  char* ws = (char*)d_ws;
  size_t off = 0;
  auto alloc = [&](size_t bytes) -> char* {
    char* p = ws + off;
    off = (off + bytes + 255) & ~(size_t)255;
    return p;
  };

  bf16* xb   = (bf16*)alloc((size_t)NN * DD * 2);
  bf16* eb   = (bf16*)alloc((size_t)NE * DD * 2);
  bf16* aggb = (bf16*)alloc((size_t)NN * DD * 2);
  bf16* eW0t = (bf16*)alloc((size_t)CW0 * 2);
  bf16* eW1t = (bf16*)alloc((size_t)CW1 * 2);
  bf16* eW2t = (bf16*)alloc((size_t)CW1 * 2);
  bf16* nW0t = (bf16*)alloc((size_t)CNW0 * 2);
  bf16* nW1t = (bf16*)alloc((size_t)CW1 * 2);
  bf16* nW2t = (bf16*)alloc((size_t)CW1 * 2);
  float* bf_[10];
  for (int i = 0; i < 10; i++) bf_[i] = (float*)alloc(CB * 4);
  int* counts = (int*)alloc((size_t)NN * 4);
  int* cursor = (int*)alloc((size_t)NN * 4);
  int* offs   = (int*)alloc((size_t)(NN + 1) * 4);
  int* sorted = (int*)alloc((size_t)NE * 4);
  int* flag   = (int*)alloc(4);

  // 1) zero counts + detect dtype
  detzero_kernel<<<80, 256, 0, stream>>>((const unsigned short*)d_in[0], counts, flag);

  // 2) all conversions in one kernel
  CvtP C;
  C.x = d_in[0]; C.e = d_in[1];
  C.w[0] = d_in[2];  C.w[1] = d_in[4];  C.w[2] = d_in[6];
  C.w[3] = d_in[10]; C.w[4] = d_in[12]; C.w[5] = d_in[14];
  C.xb = xb; C.eb = eb;
  C.wt[0] = eW0t; C.wt[1] = eW1t; C.wt[2] = eW2t;
  C.wt[3] = nW0t; C.wt[4] = nW1t; C.wt[5] = nW2t;
  const int bsrc_idx[10] = {3, 5, 7, 8, 9, 11, 13, 15, 16, 17};
  for (int i = 0; i < 10; i++) { C.bs[i] = d_in[bsrc_idx[i]]; C.bd[i] = bf_[i]; }
  C.flag = flag;
  convert_all<<<2048, 256, 0, stream>>>(C);

  // 3) CSR
  hist_kernel<<<(NE + 255) / 256, 256, 0, stream>>>(eidx, counts);
  scan_kernel<<<1, 1024, 0, stream>>>(counts, offs, cursor);
  fill_kernel<<<(NE + 255) / 256, 256, 0, stream>>>(eidx, offs, cursor, sorted);

  const int egrid = NE / 128;               // 625 (4-wave x MI=2: 128-row blocks)
  const int ngrid = (NN + 63) / 64;         // 313 (4-wave x MI=1: 64-row blocks)

  // 4) message passing: 3 dispatches per iteration
  for (int t = 0; t < NITER; t++) {
    fused_mlp<384, 1, 4, 2><<<egrid, 256, 0, stream>>>(
        xb, eb, eidx,
        eW0t + (size_t)t * 384 * DD, eW1t + (size_t)t * 128 * DD,
        eW2t + (size_t)t * 128 * DD,
        bf_[0] + t * DD, bf_[1] + t * DD, bf_[2] + t * DD,
        bf_[3] + t * DD, bf_[4] + t * DD, eb, NE);
    aggregate_kernel<<<(NN + 3) / 4, 256, 0, stream>>>(eb, offs, sorted, aggb);
    fused_mlp<256, 2, 4, 1><<<ngrid, 256, 0, stream>>>(
        xb, aggb, nullptr,
        nW0t + (size_t)t * 256 * DD, nW1t + (size_t)t * 128 * DD,
        nW2t + (size_t)t * 128 * DD,
        bf_[5] + t * DD, bf_[6] + t * DD, bf_[7] + t * DD,
        bf_[8] + t * DD, bf_[9] + t * DD, xb, NN);
  }

  // 5) output
  outwb_kernel<<<((NN + NE) * DD + 255) / 256, 256, 0, stream>>>(xb, eb, d_out, flag);
}

// Round 7
// 1065.327 us; speedup vs baseline: 2.7796x; 1.0133x over previous
//
#include <hip/hip_runtime.h>
#include <hip/hip_bf16.h>

typedef __hip_bfloat16 bf16;
typedef __attribute__((ext_vector_type(8))) short short8;
typedef __attribute__((ext_vector_type(4))) float f32x4;

#define NN 20000
#define NE 80000
#define DD 128
#define NITER 15
#define HSTRIDE 136   // 272 B row stride: 16B-aligned rows, 2-way LDS aliasing (free)

__device__ inline void gload16(const void* g, void* l) {
  __builtin_amdgcn_global_load_lds(
      (const __attribute__((address_space(1))) void*)g,
      (__attribute__((address_space(3))) void*)l, 16, 0, 0);
}

// counted vmem wait: allow exactly n newest vector-memory ops to stay in
// flight; everything older (the slab we're about to consume) must land.
__device__ inline void waitVm(int n) {
  switch (n) {
    case 0: asm volatile("s_waitcnt vmcnt(0)" ::: "memory"); break;
    case 1: asm volatile("s_waitcnt vmcnt(1)" ::: "memory"); break;
    case 2: asm volatile("s_waitcnt vmcnt(2)" ::: "memory"); break;
    case 3: asm volatile("s_waitcnt vmcnt(3)" ::: "memory"); break;
    case 4: asm volatile("s_waitcnt vmcnt(4)" ::: "memory"); break;
    case 5: asm volatile("s_waitcnt vmcnt(5)" ::: "memory"); break;
    default: asm volatile("s_waitcnt vmcnt(6)" ::: "memory"); break;
  }
}

__device__ inline float bfbits2f(unsigned int hi16) {
  union { unsigned int u; float f; } c; c.u = hi16; return c.f;
}

__device__ inline float readin(const void* p, size_t i, int fl) {
  return fl ? (float)((const bf16*)p)[i] : ((const float*)p)[i];
}

// ---------------------------------------------------------------------------
// detzero: blocks 0..78 zero counts; block 79 runs dtype detection.
// flag = 1 -> bf16 inputs ; flag = 0 -> fp32 inputs.
// ---------------------------------------------------------------------------
__global__ void detzero_kernel(const unsigned short* __restrict__ x,
                               int* __restrict__ counts, int* __restrict__ flag) {
  const int bid = blockIdx.x, t = threadIdx.x;
  if (bid < 79) {
    int i = bid * 256 + t;
    if (i < NN) counts[i] = 0;
    return;
  }
  __shared__ int cs[256], ct[256];
  int sane = 0, tot = 0;
  for (int i = 2 * t; i < 16384; i += 512) {
    unsigned short v = x[i];
    int e = (v >> 7) & 0xFF;
    tot++;
    if (v == 0 || (e >= 80 && e <= 170)) sane++;
  }
  cs[t] = sane; ct[t] = tot;
  __syncthreads();
  for (int o = 128; o > 0; o >>= 1) {
    if (t < o) { cs[t] += cs[t + o]; ct[t] += ct[t + o]; }
    __syncthreads();
  }
  if (t == 0) *flag = (cs[0] * 10 > ct[0] * 7) ? 1 : 0;
}

// ---------------------------------------------------------------------------
// convert_all: elementwise canonicalization only (x, edge_attr, biases).
// Weight transpose moved to wtrans_kernel (round-7): the old in-place
// strided write (stride K per lane) caused HBM write amplification —
// measured 52 us @ 21% peak BW with WRITE_SIZE 2x ideal.
// ---------------------------------------------------------------------------
#define CX  (NN * DD)
#define CE  (NE * DD)
#define CW0 (NITER * 384 * DD)
#define CW1 (NITER * 128 * DD)
#define CNW0 (NITER * 256 * DD)
#define CB  (NITER * DD)
#define BX0 CX
#define BX1 (BX0 + CE)
#define BX2 (BX1 + 10 * CB)

struct CvtP {
  const void *x, *e;
  bf16 *xb, *eb;
  const void* bs[10];
  float* bd[10];
  const int* flag;
};

__global__ void convert_all(CvtP P) {
  const int fl = *P.flag;
  const int gstride = gridDim.x * 256;
  for (int i = blockIdx.x * 256 + threadIdx.x; i < BX2; i += gstride) {
    if (i < BX0) {
      P.xb[i] = (bf16)readin(P.x, i, fl);
    } else if (i < BX1) {
      P.eb[i - BX0] = (bf16)readin(P.e, i - BX0, fl);
    } else {
      int j = i - BX1;
      int b = j / CB, r = j - b * CB;
      P.bd[b][r] = readin(P.bs[b], r, fl);
    }
  }
}

// ---------------------------------------------------------------------------
// wtrans_kernel: weight transpose (K x DD -> DD x K) via LDS 32x32 tiles.
// Reads coalesced over n (128 B fp32 / 64 B bf16 per row), writes coalesced
// over k (64 B bf16 segments). LDS padded [32][33] -> conflict-free both
// phases. The fused_mlp B-read bank swizzle is baked into the write k index:
// octet q = (k>>3)&3 stored at q ^ ((n>>1)&3). n is wave-uniform per row
// write, so the permutation stays within one 64 B segment (coalescing kept).
// Tile counts: w0 15*12*4=720 | w1,w2 15*4*4=240 | w3 15*8*4=480 | w4,w5 240.
// ---------------------------------------------------------------------------
struct WtP {
  const void* w[6];
  bf16* wt[6];
  const int* flag;
};

__global__ void wtrans_kernel(WtP P) {
  __shared__ float tile[32][33];
  const int fl = *P.flag;
  const int bid = blockIdx.x;
  int w, rem;
  if      (bid < 720)  { w = 0; rem = bid; }
  else if (bid < 960)  { w = 1; rem = bid - 720; }
  else if (bid < 1200) { w = 2; rem = bid - 960; }
  else if (bid < 1680) { w = 3; rem = bid - 1200; }
  else if (bid < 1920) { w = 4; rem = bid - 1680; }
  else                 { w = 5; rem = bid - 1920; }
  const int K = (w == 0) ? 384 : (w == 3) ? 256 : 128;
  const int nkt    = K >> 5;          // tiles along K
  const int per_it = nkt << 2;        // * (DD/32)
  const int it = rem / per_it;
  const int r2 = rem - it * per_it;
  const int k0 = (r2 >> 2) << 5;
  const int n0 = (r2 & 3) << 5;

  const int tx = threadIdx.x & 31, ty = threadIdx.x >> 5;   // ty 0..7
  const size_t base = (size_t)it * K * DD;

#pragma unroll
  for (int p = 0; p < 4; p++) {
    const int k = k0 + ty + 8 * p;
    tile[ty + 8 * p][tx] = readin(P.w[w], base + (size_t)k * DD + n0 + tx, fl);
  }
  __syncthreads();
#pragma unroll
  for (int p = 0; p < 4; p++) {
    const int n = n0 + ty + 8 * p;
    const int k = k0 + tx;
    const int q = (k >> 3) & 3;
    const int kp = (k & ~24) | (((q ^ ((n >> 1) & 3)) & 3) << 3);
    P.wt[w][base + (size_t)n * K + kp] = (bf16)tile[tx][ty + 8 * p];
  }
}

// ---------------------------------------------------------------------------
// Fused 3-layer MLP, NW waves x MI row-groups (16 rows each), 128-col tile.
// B staged double-buffered via global_load_lds; counted-vmcnt T4 barriers
// (round-5, measured win); A direct-to-register 1-deep prefetch; LDS-free
// LayerNorm; bf16 residual RMW.
// Round-6 (measured win): MI=2 on edge + B-read octet bank swizzle.
// Rounds 1-2: direct-B 2-3x worse than staging. Round-3: aggregate stays a
// separate fat-grid kernel.
//
// AMODE 1: A0 = concat(xb[row[m]], xb[col[m]], eb[m])  (K0=384)
// AMODE 2: A0 = concat(xb[m], aggb[m])                 (K0=256)
// ---------------------------------------------------------------------------
template<int K0, int AMODE, int NW, int MI>
__global__ __launch_bounds__(NW * 64, MI == 2 ? 3 : 4) void fused_mlp(
    const bf16* S0b,                 // xb (may alias st for AMODE 2)
    const bf16* S1b,                 // eb (AMODE 1, aliases st) / aggb (AMODE 2)
    const int*  __restrict__ eidx,
    const bf16* __restrict__ W0t, const bf16* __restrict__ W1t,
    const bf16* __restrict__ W2t,
    const float* __restrict__ b0, const float* __restrict__ b1,
    const float* __restrict__ b2,
    const float* __restrict__ gamma, const float* __restrict__ beta,
    bf16* st, int M)
{
  constexpr int NS1  = K0 / 32;      // 12 or 8 (even)
  constexpr int RPW  = 16 * MI;      // rows per wave
  constexpr int ROWS = NW * RPW;
  constexpr int DN   = 2;            // gload16 instrs per dmaW (256 threads)
  __shared__ __align__(16) bf16 Bls[2][128 * 32];
  __shared__ __align__(16) bf16 Hls[ROWS * HSTRIDE];

  const int tid  = threadIdx.x;
  const int lane = tid & 63;
  const int wv   = tid >> 6;
  const int l15  = lane & 15, quad = lane >> 4;
  const int m0   = blockIdx.x * ROWS;
  const int scol = tid >> 2;
  const int sk8  = (tid & 3) * 8;

  int rowm[MI], ir[MI], ic[MI];
#pragma unroll
  for (int g = 0; g < MI; g++) {
    rowm[g] = min(m0 + wv * RPW + g * 16 + l15, M - 1);
    ir[g] = 0; ic[g] = 0;
    if (AMODE == 1) { ir[g] = eidx[rowm[g]]; ic[g] = eidx[NE + rowm[g]]; }
  }

  auto dmaW = [&](const bf16* W, int K, int kk, int buf) {
    gload16(W + (size_t)scol * K + kk + sk8,        &Bls[buf][scol * 32 + sk8]);
    gload16(W + (size_t)(scol + 64) * K + kk + sk8, &Bls[buf][(scol + 64) * 32 + sk8]);
  };
  auto gatherA = [&](int g, int kk, short8* a) {
    const int ks = (kk & 127) + quad * 8;
    const bf16* base;
    if (AMODE == 1) {
      const int seg = kk >> 7;
      base = (seg == 0) ? S0b + (size_t)ir[g] * DD
           : (seg == 1) ? S0b + (size_t)ic[g] * DD
                        : S1b + (size_t)rowm[g] * DD;
    } else {
      base = (kk >> 7) ? S1b + (size_t)rowm[g] * DD
                       : S0b + (size_t)rowm[g] * DD;
    }
    *a = *(const short8*)(base + ks);
  };

  // swizzled B-fragment read (matches wtrans_kernel's octet permutation)
  auto readB = [&](int buf, short8* bfr) {
#pragma unroll
    for (int ni = 0; ni < 8; ni++) {
      const int r = ni * 16 + l15;
      bfr[ni] = *(const short8*)&Bls[buf][r * 32 + ((quad ^ ((r >> 1) & 3)) & 3) * 8];
    }
  };

  f32x4 acc[MI][8];
  auto zacc = [&]() {
#pragma unroll
    for (int g = 0; g < MI; g++)
#pragma unroll
      for (int j = 0; j < 8; j++) acc[g][j] = (f32x4){0.f, 0.f, 0.f, 0.f};
  };
  auto slabMfmaA = [&](short8* a, int buf) {
    short8 bfr[8];
    readB(buf, bfr);
#pragma unroll
    for (int g = 0; g < MI; g++)
#pragma unroll
      for (int ni = 0; ni < 8; ni++)
        acc[g][ni] = __builtin_amdgcn_mfma_f32_16x16x32_bf16(a[g], bfr[ni], acc[g][ni], 0, 0, 0);
  };
  auto slabMfmaH = [&](int kk, int buf) {
    short8 bfr[8];
    readB(buf, bfr);
#pragma unroll
    for (int g = 0; g < MI; g++) {
      short8 a = *(const short8*)&Hls[(wv * RPW + g * 16 + l15) * HSTRIDE + kk + quad * 8];
#pragma unroll
      for (int ni = 0; ni < 8; ni++)
        acc[g][ni] = __builtin_amdgcn_mfma_f32_16x16x32_bf16(a, bfr[ni], acc[g][ni], 0, 0, 0);
    }
  };
  auto writeH = [&](const float* bias) {
    float bv[8];
#pragma unroll
    for (int ni = 0; ni < 8; ni++) bv[ni] = bias[ni * 16 + l15];
#pragma unroll
    for (int g = 0; g < MI; g++)
#pragma unroll
      for (int r = 0; r < 4; r++) {
        const int row = wv * RPW + g * 16 + quad * 4 + r;
#pragma unroll
        for (int ni = 0; ni < 8; ni++)
          Hls[row * HSTRIDE + ni * 16 + l15] = (bf16)fmaxf(acc[g][ni][r] + bv[ni], 0.f);
      }
  };

  // Phase 1
  zacc();
  short8 aCur[MI], aNxt[MI];
  dmaW(W0t, K0, 0, 0);
#pragma unroll
  for (int g = 0; g < MI; g++) gatherA(g, 0, &aCur[g]);
#pragma unroll
  for (int s = 0; s < NS1; s++) {
    int cnt;
    if (s + 1 < NS1) {
      dmaW(W0t, K0, (s + 1) * 32, (s + 1) & 1);
#pragma unroll
      for (int g = 0; g < MI; g++) gatherA(g, (s + 1) * 32, &aNxt[g]);
      cnt = MI + DN + MI;            // gatherA(s) + DMA(s+1) + gatherA(s+1)
    } else {
      dmaW(W1t, 128, 0, NS1 & 1);
      cnt = MI + DN;                 // gatherA(s) + DMA(next)
    }
    waitVm(cnt);
    __builtin_amdgcn_s_barrier();
    __builtin_amdgcn_sched_barrier(0);
    slabMfmaA(aCur, s & 1);
    __builtin_amdgcn_sched_barrier(0);
    __builtin_amdgcn_s_barrier();
#pragma unroll
    for (int g = 0; g < MI; g++) aCur[g] = aNxt[g];
  }
  writeH(b0);

  // Phase 2
  zacc();
#pragma unroll
  for (int s = 0; s < 4; s++) {
    if (s < 3) dmaW(W1t, 128, (s + 1) * 32, (NS1 + s + 1) & 1);
    else       dmaW(W2t, 128, 0,            (NS1 + 4) & 1);
    waitVm(DN);                      // allow this iter's DMA in flight
    __builtin_amdgcn_s_barrier();
    __builtin_amdgcn_sched_barrier(0);
    slabMfmaH(s * 32, (NS1 + s) & 1);
    __builtin_amdgcn_sched_barrier(0);
    __builtin_amdgcn_s_barrier();
  }
  writeH(b1);

  // Phase 3 + LN + residual
  zacc();
#pragma unroll
  for (int s = 0; s < 4; s++) {
    int cnt = 0;
    if (s < 3) { dmaW(W2t, 128, (s + 1) * 32, (NS1 + 4 + s + 1) & 1); cnt = DN; }
    waitVm(cnt);
    __builtin_amdgcn_s_barrier();
    __builtin_amdgcn_sched_barrier(0);
    slabMfmaH(s * 32, (NS1 + 4 + s) & 1);
    if (s < 3) {
      __builtin_amdgcn_sched_barrier(0);
      __builtin_amdgcn_s_barrier();
    }
  }

  float bv[8], gv[8], btv[8];
#pragma unroll
  for (int ni = 0; ni < 8; ni++) {
    const int col = ni * 16 + l15;
    bv[ni] = b2[col]; gv[ni] = gamma[col]; btv[ni] = beta[col];
  }
#pragma unroll
  for (int g = 0; g < MI; g++) {
#pragma unroll
    for (int r = 0; r < 4; r++) {
      float a = 0.f, bq = 0.f;
#pragma unroll
      for (int ni = 0; ni < 8; ni++) {
        const float v = acc[g][ni][r] + bv[ni];
        a += v; bq += v * v;
      }
#pragma unroll
      for (int off = 1; off < 16; off <<= 1) {
        a  += __shfl_xor(a, off);
        bq += __shfl_xor(bq, off);
      }
      const float mu = a * (1.0f / 128.0f);
      const float var = fmaxf(bq * (1.0f / 128.0f) - mu * mu, 0.0f);
      const float rs = rsqrtf(var + 1e-5f);
      const int m = m0 + wv * RPW + g * 16 + quad * 4 + r;
      if (m < M) {
#pragma unroll
        for (int ni = 0; ni < 8; ni++) {
          const int col = ni * 16 + l15;
          const float v = acc[g][ni][r] + bv[ni];
          const float lnv = (v - mu) * rs * gv[ni] + btv[ni];
          const size_t idx = (size_t)m * DD + col;
          st[idx] = (bf16)(lnv + (float)st[idx]);
        }
      }
    }
  }
}

// --------------------------- CSR build + aggregate -------------------------
__global__ void hist_kernel(const int* __restrict__ eidx, int* __restrict__ counts) {
  int e = blockIdx.x * 256 + threadIdx.x;
  if (e < NE) atomicAdd(&counts[eidx[NE + e]], 1);
}

__global__ void scan_kernel(const int* __restrict__ counts, int* __restrict__ offs,
                            int* __restrict__ cursor) {
  __shared__ int sums[1024];
  const int t = threadIdx.x;
  const int base = t * 20;
  int local[20];
  int s = 0;
  for (int i = 0; i < 20; i++) {
    int idx = base + i;
    int c = (idx < NN) ? counts[idx] : 0;
    local[i] = s; s += c;
  }
  sums[t] = s;
  __syncthreads();
  for (int off = 1; off < 1024; off <<= 1) {
    int v = 0;
    if (t >= off) v = sums[t - off];
    __syncthreads();
    if (t >= off) sums[t] += v;
    __syncthreads();
  }
  int excl = (t == 0) ? 0 : sums[t - 1];
  for (int i = 0; i < 20; i++) {
    int idx = base + i;
    if (idx < NN) { offs[idx] = excl + local[i]; cursor[idx] = 0; }
  }
  if (t == 1023) offs[NN] = sums[1023];
}

__global__ void fill_kernel(const int* __restrict__ eidx, const int* __restrict__ offs,
                            int* __restrict__ cursor, int* __restrict__ sorted) {
  int e = blockIdx.x * 256 + threadIdx.x;
  if (e < NE) {
    int n = eidx[NE + e];
    int p = atomicAdd(&cursor[n], 1);
    sorted[offs[n] + p] = e;
  }
}

// wave per node (fat grid: 20000 waves, 32 waves/CU -> latency well hidden):
// packed-uint bf16x2 loads, fp32 sums, bf16 out.
__global__ void aggregate_kernel(const bf16* __restrict__ eb, const int* __restrict__ offs,
                                 const int* __restrict__ sorted, bf16* __restrict__ aggb) {
  const int node = blockIdx.x * 4 + (threadIdx.x >> 6);
  const int lane = threadIdx.x & 63;
  if (node >= NN) return;
  const int s = offs[node], t = offs[node + 1];
  float a0 = 0.f, a1 = 0.f;
  for (int i = s; i < t; i++) {
    const int e = sorted[i];
    unsigned int v = *(const unsigned int*)(eb + (size_t)e * DD + 2 * lane);
    a0 += bfbits2f(v << 16);
    a1 += bfbits2f(v & 0xFFFF0000u);
  }
  bf16 o0 = (bf16)a0, o1 = (bf16)a1;
  unsigned int pack = (unsigned int)(*(unsigned short*)&o0)
                    | ((unsigned int)(*(unsigned short*)&o1) << 16);
  *(unsigned int*)(aggb + (size_t)node * DD + 2 * lane) = pack;
}

// bf16 states -> d_out in detected dtype
__global__ void outwb_kernel(const bf16* __restrict__ xb, const bf16* __restrict__ eb,
                             void* __restrict__ out, const int* __restrict__ flag) {
  int i = blockIdx.x * 256 + threadIdx.x;
  const int nx = NN * DD, total = (NN + NE) * DD;
  if (i < total) {
    bf16 v = (i < nx) ? xb[i] : eb[i - nx];
    if (*flag) ((bf16*)out)[i] = v;
    else       ((float*)out)[i] = (float)v;
  }
}

// ---------------------------------------------------------------------------
extern "C" void kernel_launch(void* const* d_in, const int* in_sizes, int n_in,
                              void* d_out, int out_size, void* d_ws, size_t ws_size,
                              hipStream_t stream) {
  const int* eidx = (const int*)d_in[18];

  char* ws = (char*)d_ws;
  size_t off = 0;
  auto alloc = [&](size_t bytes) -> char* {
    char* p = ws + off;
    off = (off + bytes + 255) & ~(size_t)255;
    return p;
  };

  bf16* xb   = (bf16*)alloc((size_t)NN * DD * 2);
  bf16* eb   = (bf16*)alloc((size_t)NE * DD * 2);
  bf16* aggb = (bf16*)alloc((size_t)NN * DD * 2);
  bf16* eW0t = (bf16*)alloc((size_t)CW0 * 2);
  bf16* eW1t = (bf16*)alloc((size_t)CW1 * 2);
  bf16* eW2t = (bf16*)alloc((size_t)CW1 * 2);
  bf16* nW0t = (bf16*)alloc((size_t)CNW0 * 2);
  bf16* nW1t = (bf16*)alloc((size_t)CW1 * 2);
  bf16* nW2t = (bf16*)alloc((size_t)CW1 * 2);
  float* bf_[10];
  for (int i = 0; i < 10; i++) bf_[i] = (float*)alloc(CB * 4);
  int* counts = (int*)alloc((size_t)NN * 4);
  int* cursor = (int*)alloc((size_t)NN * 4);
  int* offs   = (int*)alloc((size_t)(NN + 1) * 4);
  int* sorted = (int*)alloc((size_t)NE * 4);
  int* flag   = (int*)alloc(4);

  // 1) zero counts + detect dtype
  detzero_kernel<<<80, 256, 0, stream>>>((const unsigned short*)d_in[0], counts, flag);

  // 2) elementwise conversions + LDS-tiled weight transpose
  CvtP C;
  C.x = d_in[0]; C.e = d_in[1];
  C.xb = xb; C.eb = eb;
  const int bsrc_idx[10] = {3, 5, 7, 8, 9, 11, 13, 15, 16, 17};
  for (int i = 0; i < 10; i++) { C.bs[i] = d_in[bsrc_idx[i]]; C.bd[i] = bf_[i]; }
  C.flag = flag;
  convert_all<<<2048, 256, 0, stream>>>(C);

  WtP W;
  W.w[0] = d_in[2];  W.w[1] = d_in[4];  W.w[2] = d_in[6];
  W.w[3] = d_in[10]; W.w[4] = d_in[12]; W.w[5] = d_in[14];
  W.wt[0] = eW0t; W.wt[1] = eW1t; W.wt[2] = eW2t;
  W.wt[3] = nW0t; W.wt[4] = nW1t; W.wt[5] = nW2t;
  W.flag = flag;
  wtrans_kernel<<<2160, 256, 0, stream>>>(W);

  // 3) CSR
  hist_kernel<<<(NE + 255) / 256, 256, 0, stream>>>(eidx, counts);
  scan_kernel<<<1, 1024, 0, stream>>>(counts, offs, cursor);
  fill_kernel<<<(NE + 255) / 256, 256, 0, stream>>>(eidx, offs, cursor, sorted);

  const int egrid = NE / 128;               // 625 (4-wave x MI=2: 128-row blocks)
  const int ngrid = (NN + 63) / 64;         // 313 (4-wave x MI=1: 64-row blocks)

  // 4) message passing: 3 dispatches per iteration
  for (int t = 0; t < NITER; t++) {
    fused_mlp<384, 1, 4, 2><<<egrid, 256, 0, stream>>>(
        xb, eb, eidx,
        eW0t + (size_t)t * 384 * DD, eW1t + (size_t)t * 128 * DD,
        eW2t + (size_t)t * 128 * DD,
        bf_[0] + t * DD, bf_[1] + t * DD, bf_[2] + t * DD,
        bf_[3] + t * DD, bf_[4] + t * DD, eb, NE);
    aggregate_kernel<<<(NN + 3) / 4, 256, 0, stream>>>(eb, offs, sorted, aggb);
    fused_mlp<256, 2, 4, 1><<<ngrid, 256, 0, stream>>>(
        xb, aggb, nullptr,
        nW0t + (size_t)t * 256 * DD, nW1t + (size_t)t * 128 * DD,
        nW2t + (size_t)t * 128 * DD,
        bf_[5] + t * DD, bf_[6] + t * DD, bf_[7] + t * DD,
        bf_[8] + t * DD, bf_[9] + t * DD, xb, NN);
  }

  // 5) output
  outwb_kernel<<<((NN + NE) * DD + 255) / 256, 256, 0, stream>>>(xb, eb, d_out, flag);
}